// Round 2
// baseline (744.388 us; speedup 1.0000x reference)
//
#include <hip/hip_runtime.h>

#define S_ 2048
#define D_ 1024
#define B_ 2
#define H_ 16
#define DK_ 64
#define HID_ 4096

typedef unsigned short u16;
typedef __attribute__((ext_vector_type(8))) short short8;
typedef __attribute__((ext_vector_type(4))) float f32x4;

__device__ __forceinline__ float bf2f(u16 u) {
  return __uint_as_float(((unsigned int)u) << 16);
}
__device__ __forceinline__ u16 f2bf(float f) {
  unsigned int x = __float_as_uint(f);
  x += 0x7fff + ((x >> 16) & 1);
  return (u16)(x >> 16);
}

// ---------------- fp32 -> bf16 convert (4 elems/thread) ----------------
__global__ __launch_bounds__(256) void cvt_f2b(const float* __restrict__ in, u16* __restrict__ outp) {
  const int i = blockIdx.x * 256 + threadIdx.x;
  float4 v = ((const float4*)in)[i];
  unsigned int lo = (unsigned int)f2bf(v.x) | ((unsigned int)f2bf(v.y) << 16);
  unsigned int hi = (unsigned int)f2bf(v.z) | ((unsigned int)f2bf(v.w) << 16);
  ((uint2*)outp)[i] = make_uint2(lo, hi);
}

// ---------------- generic bf16 GEMM: C[M,N] = A[M,K] @ Bt[N,K]^T (+fp32 bias, relu) ----
// BM=MT*32, BN=NT*32, BK=32. 4 waves in 2x2; wave computes (MT*16) x (NT*16).
template<int MT, int NT>
__global__ __launch_bounds__(256) void gemm_bt(
    const u16* __restrict__ A, const u16* __restrict__ Bt,
    const float* __restrict__ bias, u16* __restrict__ C,
    int K, int lda, int ldb, int ldc,
    long sA, long sB, long sC, int relu) {
  constexpr int BM = MT * 32;
  constexpr int BN = NT * 32;
  __shared__ __align__(16) u16 As[BM * 32];
  __shared__ __align__(16) u16 Bs[BN * 32];
  const int z = blockIdx.z;
  A  += (long)z * sA;
  Bt += (long)z * sB;
  C  += (long)z * sC;
  const int tid  = threadIdx.x;
  const int lane = tid & 63, wave = tid >> 6;
  const int quad = lane >> 4, l15 = lane & 15;
  const int wm = wave >> 1, wn = wave & 1;
  const u16* Ab = A  + (long)(blockIdx.y * BM) * lda;
  const u16* Bb = Bt + (long)(blockIdx.x * BN) * ldb;

  f32x4 acc[MT][NT];
#pragma unroll
  for (int i = 0; i < MT; ++i)
#pragma unroll
    for (int j = 0; j < NT; ++j) acc[i][j] = (f32x4){0.f, 0.f, 0.f, 0.f};

  const int r0  = tid >> 2;        // staging row within 64-row pass
  const int kk0 = (tid & 3) * 8;   // staging k-offset (8 bf16 = 16B)

  for (int kt = 0; kt < K; kt += 32) {
#pragma unroll
    for (int p = 0; p < BM / 64; ++p) {
      __builtin_amdgcn_global_load_lds(
          (const __attribute__((address_space(1))) void*)(Ab + (long)(p * 64 + r0) * lda + kt + kk0),
          (__attribute__((address_space(3))) void*)(&As[p * 2048 + tid * 8]), 16, 0, 0);
    }
#pragma unroll
    for (int p = 0; p < BN / 64; ++p) {
      __builtin_amdgcn_global_load_lds(
          (const __attribute__((address_space(1))) void*)(Bb + (long)(p * 64 + r0) * ldb + kt + kk0),
          (__attribute__((address_space(3))) void*)(&Bs[p * 2048 + tid * 8]), 16, 0, 0);
    }
    __syncthreads();
    short8 af[MT], bfr[NT];
#pragma unroll
    for (int mt = 0; mt < MT; ++mt)
      af[mt] = *(const short8*)&As[(wm * (MT * 16) + mt * 16 + l15) * 32 + quad * 8];
#pragma unroll
    for (int nt = 0; nt < NT; ++nt)
      bfr[nt] = *(const short8*)&Bs[(wn * (NT * 16) + nt * 16 + l15) * 32 + quad * 8];
#pragma unroll
    for (int mt = 0; mt < MT; ++mt)
#pragma unroll
      for (int nt = 0; nt < NT; ++nt)
        acc[mt][nt] = __builtin_amdgcn_mfma_f32_16x16x32_bf16(af[mt], bfr[nt], acc[mt][nt], 0, 0, 0);
    __syncthreads();
  }

  // epilogue: C/D layout col=lane&15, row=quad*4+reg
#pragma unroll
  for (int nt = 0; nt < NT; ++nt) {
    const int col = blockIdx.x * BN + wn * (NT * 16) + nt * 16 + l15;
    const float bvv = bias ? bias[col] : 0.f;
#pragma unroll
    for (int mt = 0; mt < MT; ++mt) {
#pragma unroll
      for (int r = 0; r < 4; ++r) {
        const int row = blockIdx.y * BM + wm * (MT * 16) + mt * 16 + quad * 4 + r;
        float v = acc[mt][nt][r] + bvv;
        if (relu) v = fmaxf(v, 0.f);
        C[(long)row * ldc + col] = f2bf(v);
      }
    }
  }
}

// ---------------- transpose + convert: out_bf16[C,R] = in_f32[R,C] ----------------
__global__ void transpose_k(const float* __restrict__ in, u16* __restrict__ outp, int R, int Ccols) {
  __shared__ u16 tile[32][33];
  const int c0 = blockIdx.x * 32, r0 = blockIdx.y * 32;
  const int tx = threadIdx.x, ty = threadIdx.y;
  for (int i = ty; i < 32; i += 8)
    tile[i][tx] = f2bf(in[(long)(r0 + i) * Ccols + c0 + tx]);
  __syncthreads();
  for (int i = ty; i < 32; i += 8)
    outp[(long)(c0 + i) * R + r0 + tx] = tile[tx][i];
}

// ---------------- V[b,s,h*64+d] -> Vt[bh][d][s]  (bf16 in/out) ----------------
__global__ void vtrans_k(const u16* __restrict__ V, u16* __restrict__ Vt) {
  __shared__ u16 tile[32][33];
  const int bh = blockIdx.z, b = bh >> 4, h = bh & 15;
  const u16* in = V + (long)b * S_ * D_ + h * DK_;
  u16* outp = Vt + (long)bh * DK_ * S_;
  const int s0 = blockIdx.x * 32, d0 = blockIdx.y * 32;
  const int tx = threadIdx.x, ty = threadIdx.y;
  for (int i = ty; i < 32; i += 8)
    tile[i][tx] = in[(long)(s0 + i) * D_ + d0 + tx];
  __syncthreads();
  for (int i = ty; i < 32; i += 8)
    outp[(long)(d0 + i) * S_ + s0 + tx] = tile[tx][i];
}

// ---------------- masked softmax over P rows (in-place, bf16), scale=1/8 ----------------
__global__ __launch_bounds__(256) void softmax_k(u16* __restrict__ P, const int* __restrict__ mask, int bh0) {
  __shared__ float red[4];
  const int rowid = blockIdx.x;
  const int bh = bh0 + (rowid >> 11);
  const int b = bh >> 4;
  u16* prow = P + (long)rowid * 2048;
  const int tid = threadIdx.x;
  uint4 dv = ((const uint4*)prow)[tid];
  unsigned int uu[4] = {dv.x, dv.y, dv.z, dv.w};
  float s[8];
#pragma unroll
  for (int j = 0; j < 4; ++j) {
    s[2 * j]     = bf2f((u16)(uu[j] & 0xffff)) * 0.125f;
    s[2 * j + 1] = bf2f((u16)(uu[j] >> 16)) * 0.125f;
  }
  const int* mrow = mask + b * S_;
  const int k0 = tid * 8;
#pragma unroll
  for (int j = 0; j < 8; ++j)
    if (mrow[k0 + j] == 0) s[j] = -1e9f;
  float mx = s[0];
#pragma unroll
  for (int j = 1; j < 8; ++j) mx = fmaxf(mx, s[j]);
#pragma unroll
  for (int off = 32; off; off >>= 1) mx = fmaxf(mx, __shfl_down(mx, off, 64));
  if ((tid & 63) == 0) red[tid >> 6] = mx;
  __syncthreads();
  mx = fmaxf(fmaxf(red[0], red[1]), fmaxf(red[2], red[3]));
  __syncthreads();
  float sum = 0.f;
#pragma unroll
  for (int j = 0; j < 8; ++j) { s[j] = __expf(s[j] - mx); sum += s[j]; }
#pragma unroll
  for (int off = 32; off; off >>= 1) sum += __shfl_down(sum, off, 64);
  if ((tid & 63) == 0) red[tid >> 6] = sum;
  __syncthreads();
  sum = red[0] + red[1] + red[2] + red[3];
  const float inv = 1.f / sum;
#pragma unroll
  for (int j = 0; j < 4; ++j) {
    u16 lo = f2bf(s[2 * j] * inv), hi = f2bf(s[2 * j + 1] * inv);
    uu[j] = (unsigned int)lo | ((unsigned int)hi << 16);
  }
  ((uint4*)prow)[tid] = make_uint4(uu[0], uu[1], uu[2], uu[3]);
}

// ---------------- add + layernorm helpers ----------------
__device__ __forceinline__ float block_reduce_sum(float v, float* red) {
#pragma unroll
  for (int off = 32; off; off >>= 1) v += __shfl_down(v, off, 64);
  __syncthreads();
  if ((threadIdx.x & 63) == 0) red[threadIdx.x >> 6] = v;
  __syncthreads();
  return red[0] + red[1] + red[2] + red[3];
}

// x (fp32) + mha (bf16) -> LN -> x1 (bf16)
__global__ __launch_bounds__(256) void addln_fb(const float* __restrict__ A, const u16* __restrict__ Bres,
    const float* __restrict__ g, const float* __restrict__ be, u16* __restrict__ outp) {
  __shared__ float red[4];
  const int row = blockIdx.x, tid = threadIdx.x;
  const float4 av = ((const float4*)(A + (long)row * D_))[tid];
  const uint2 bv2 = ((const uint2*)(Bres + (long)row * D_))[tid];
  float xv[4];
  xv[0] = av.x + bf2f((u16)(bv2.x & 0xffff));
  xv[1] = av.y + bf2f((u16)(bv2.x >> 16));
  xv[2] = av.z + bf2f((u16)(bv2.y & 0xffff));
  xv[3] = av.w + bf2f((u16)(bv2.y >> 16));
  float s  = xv[0] + xv[1] + xv[2] + xv[3];
  float ss = xv[0]*xv[0] + xv[1]*xv[1] + xv[2]*xv[2] + xv[3]*xv[3];
  s  = block_reduce_sum(s, red);
  ss = block_reduce_sum(ss, red);
  const float m   = s * (1.0f / 1024.0f);
  const float var = ss * (1.0f / 1024.0f) - m * m;
  const float rs  = rsqrtf(var + 1e-5f);
  const int c0 = tid * 4;
  float v0 = (xv[0] - m) * rs * g[c0 + 0] + be[c0 + 0];
  float v1 = (xv[1] - m) * rs * g[c0 + 1] + be[c0 + 1];
  float v2 = (xv[2] - m) * rs * g[c0 + 2] + be[c0 + 2];
  float v3 = (xv[3] - m) * rs * g[c0 + 3] + be[c0 + 3];
  unsigned int o01 = (unsigned int)f2bf(v0) | ((unsigned int)f2bf(v1) << 16);
  unsigned int o23 = (unsigned int)f2bf(v2) | ((unsigned int)f2bf(v3) << 16);
  ((uint2*)(outp + (long)row * D_))[tid] = make_uint2(o01, o23);
}

// x1 (bf16) + ff (bf16) -> LN -> out (fp32)
__global__ __launch_bounds__(256) void addln_bf(const u16* __restrict__ A, const u16* __restrict__ Bres,
    const float* __restrict__ g, const float* __restrict__ be, float* __restrict__ outp) {
  __shared__ float red[4];
  const int row = blockIdx.x, tid = threadIdx.x;
  const uint2 av  = ((const uint2*)(A    + (long)row * D_))[tid];
  const uint2 bv2 = ((const uint2*)(Bres + (long)row * D_))[tid];
  float xv[4];
  xv[0] = bf2f((u16)(av.x & 0xffff)) + bf2f((u16)(bv2.x & 0xffff));
  xv[1] = bf2f((u16)(av.x >> 16))    + bf2f((u16)(bv2.x >> 16));
  xv[2] = bf2f((u16)(av.y & 0xffff)) + bf2f((u16)(bv2.y & 0xffff));
  xv[3] = bf2f((u16)(av.y >> 16))    + bf2f((u16)(bv2.y >> 16));
  float s  = xv[0] + xv[1] + xv[2] + xv[3];
  float ss = xv[0]*xv[0] + xv[1]*xv[1] + xv[2]*xv[2] + xv[3]*xv[3];
  s  = block_reduce_sum(s, red);
  ss = block_reduce_sum(ss, red);
  const float m   = s * (1.0f / 1024.0f);
  const float var = ss * (1.0f / 1024.0f) - m * m;
  const float rs  = rsqrtf(var + 1e-5f);
  const int c0 = tid * 4;
  float4 o;
  o.x = (xv[0] - m) * rs * g[c0 + 0] + be[c0 + 0];
  o.y = (xv[1] - m) * rs * g[c0 + 1] + be[c0 + 1];
  o.z = (xv[2] - m) * rs * g[c0 + 2] + be[c0 + 2];
  o.w = (xv[3] - m) * rs * g[c0 + 3] + be[c0 + 3];
  ((float4*)(outp + (long)row * D_))[tid] = o;
}

extern "C" void kernel_launch(void* const* d_in, const int* in_sizes, int n_in,
                              void* d_out, int out_size, void* d_ws, size_t ws_size,
                              hipStream_t stream) {
  const float* x   = (const float*)d_in[0];
  const float* y   = (const float*)d_in[1];
  const int* mask  = (const int*)d_in[2];
  const float* Wq = (const float*)d_in[3];  const float* bq = (const float*)d_in[4];
  const float* Wk = (const float*)d_in[5];  const float* bk = (const float*)d_in[6];
  const float* Wv = (const float*)d_in[7];  const float* bv = (const float*)d_in[8];
  const float* Wo = (const float*)d_in[9];  const float* bo = (const float*)d_in[10];
  const float* W1 = (const float*)d_in[11]; const float* b1 = (const float*)d_in[12];
  const float* W2 = (const float*)d_in[13]; const float* b2 = (const float*)d_in[14];
  const float* g1 = (const float*)d_in[15]; const float* be1 = (const float*)d_in[16];
  const float* g2 = (const float*)d_in[17]; const float* be2 = (const float*)d_in[18];
  float* out = (float*)d_out;

  char* w = (char*)d_ws;
  const size_t MB = 1024 * 1024;
  u16* WqT = (u16*)(w + 0 * MB);   // 2MB each, bf16 [N,K]
  u16* WkT = (u16*)(w + 2 * MB);
  u16* WvT = (u16*)(w + 4 * MB);
  u16* WoT = (u16*)(w + 6 * MB);
  u16* W1T = (u16*)(w + 8 * MB);   // 8MB  [HID][D]
  u16* W2T = (u16*)(w + 16 * MB);  // 8MB  [D][HID]
  u16* xb  = (u16*)(w + 24 * MB);  // 8MB  bf16 x
  u16* yb  = (u16*)(w + 32 * MB);  // 8MB  bf16 y
  u16* Q   = (u16*)(w + 40 * MB);  // 8MB   (reused as x1 after attention)
  u16* Kp  = (u16*)(w + 48 * MB);  // 8MB   (reused as ff after attention)
  u16* Vp  = (u16*)(w + 56 * MB);  // 8MB   (reused as mha after vtrans)
  u16* Vt  = (u16*)(w + 64 * MB);  // 8MB  [bh][d][s]
  u16* ctx = (u16*)(w + 72 * MB);  // 8MB
  u16* P   = (u16*)(w + 80 * MB);  // 64MB (attention, 8 heads/chunk)
  u16* h1  = (u16*)(w + 80 * MB);  // 32MB (FFN phase, reuses P)
  u16* mha = Vp;
  u16* x1  = Q;
  u16* ff  = Kp;                    // total footprint: 144MB

  dim3 t328(32, 8);
  // weight transposes + convert ([K,N] f32 -> [N,K] bf16)
  transpose_k<<<dim3(32, 32), t328, 0, stream>>>(Wq, WqT, 1024, 1024);
  transpose_k<<<dim3(32, 32), t328, 0, stream>>>(Wk, WkT, 1024, 1024);
  transpose_k<<<dim3(32, 32), t328, 0, stream>>>(Wv, WvT, 1024, 1024);
  transpose_k<<<dim3(32, 32), t328, 0, stream>>>(Wo, WoT, 1024, 1024);
  transpose_k<<<dim3(128, 32), t328, 0, stream>>>(W1, W1T, 1024, 4096);
  transpose_k<<<dim3(32, 128), t328, 0, stream>>>(W2, W2T, 4096, 1024);
  // activations f32 -> bf16
  cvt_f2b<<<dim3(4096), 256, 0, stream>>>(x, xb);
  cvt_f2b<<<dim3(4096), 256, 0, stream>>>(y, yb);

  // projections: [4096,1024] = [4096,1024] @ [1024,1024]
  gemm_bt<4,4><<<dim3(8, 32, 1), 256, 0, stream>>>(xb, WqT, bq, Q,  1024, 1024, 1024, 1024, 0, 0, 0, 0);
  gemm_bt<4,4><<<dim3(8, 32, 1), 256, 0, stream>>>(yb, WkT, bk, Kp, 1024, 1024, 1024, 1024, 0, 0, 0, 0);
  gemm_bt<4,4><<<dim3(8, 32, 1), 256, 0, stream>>>(yb, WvT, bv, Vp, 1024, 1024, 1024, 1024, 0, 0, 0, 0);

  vtrans_k<<<dim3(64, 2, 32), t328, 0, stream>>>(Vp, Vt);

  // attention in chunks of 8 (b,h) pairs
  for (int c = 0; c < 4; ++c) {
    const int b0 = c >> 1, hbase = (c & 1) * 8;
    const u16* Abase = Q  + (long)b0 * S_ * D_ + hbase * DK_;
    const u16* Bbase = Kp + (long)b0 * S_ * D_ + hbase * DK_;
    // scores: [2048,2048] = Q[2048,64] @ K[2048,64]^T, batched over 8 heads
    gemm_bt<4,4><<<dim3(16, 16, 8), 256, 0, stream>>>(Abase, Bbase, nullptr, P,
        64, 1024, 1024, 2048, 64, 64, (long)S_ * S_, 0);
    softmax_k<<<dim3(8 * 2048), 256, 0, stream>>>(P, mask, c * 8);
    // ctx: [2048,64] = P[2048,2048] @ Vt[64,2048]^T  (64x64 tiles for occupancy)
    gemm_bt<2,2><<<dim3(1, 32, 8), 256, 0, stream>>>(P, Vt + (long)c * 8 * DK_ * S_, nullptr,
        ctx + (long)b0 * S_ * D_ + hbase * DK_,
        2048, 2048, 2048, 1024, (long)S_ * S_, (long)DK_ * S_, 64, 0);
  }

  // output projection + LN1
  gemm_bt<4,4><<<dim3(8, 32, 1), 256, 0, stream>>>(ctx, WoT, bo, mha, 1024, 1024, 1024, 1024, 0, 0, 0, 0);
  addln_fb<<<dim3(4096), 256, 0, stream>>>(x, mha, g1, be1, x1);
  // FFN
  gemm_bt<4,4><<<dim3(32, 32, 1), 256, 0, stream>>>(x1, W1T, b1, h1, 1024, 1024, 1024, 4096, 0, 0, 0, 1);
  gemm_bt<4,4><<<dim3(8, 32, 1), 256, 0, stream>>>(h1, W2T, b2, ff, 4096, 4096, 4096, 1024, 0, 0, 0, 0);
  addln_bf<<<dim3(4096), 256, 0, stream>>>(x1, ff, g2, be2, out);
}

// Round 3
// 472.296 us; speedup vs baseline: 1.5761x; 1.5761x over previous
//
#include <hip/hip_runtime.h>

#define S_ 2048
#define D_ 1024
#define B_ 2
#define H_ 16
#define DK_ 64
#define HID_ 4096

typedef unsigned short u16;
typedef __attribute__((ext_vector_type(8))) short short8;
typedef __attribute__((ext_vector_type(4))) float f32x4;

__device__ __forceinline__ float bf2f(u16 u) {
  return __uint_as_float(((unsigned int)u) << 16);
}
__device__ __forceinline__ u16 f2bf(float f) {
  unsigned int x = __float_as_uint(f);
  x += 0x7fff + ((x >> 16) & 1);
  return (u16)(x >> 16);
}

// ---------------- fp32 -> bf16 convert (4 elems/thread) ----------------
__global__ __launch_bounds__(256) void cvt_f2b(const float* __restrict__ in, u16* __restrict__ outp) {
  const int i = blockIdx.x * 256 + threadIdx.x;
  float4 v = ((const float4*)in)[i];
  unsigned int lo = (unsigned int)f2bf(v.x) | ((unsigned int)f2bf(v.y) << 16);
  unsigned int hi = (unsigned int)f2bf(v.z) | ((unsigned int)f2bf(v.w) << 16);
  ((uint2*)outp)[i] = make_uint2(lo, hi);
}

// ---------------- generic bf16 GEMM: C[M,N] = A[M,K] @ Bt[N,K]^T ----------------
// BM=MT*32, BN=NT*32, BK=32. 4 waves 2x2. OUTF32: write float (split-K partial).
template<int MT, int NT, int OUTF32>
__global__ __launch_bounds__(256) void gemm_bt(
    const u16* __restrict__ A, const u16* __restrict__ Bt,
    const float* __restrict__ bias, void* __restrict__ Cv,
    int K, int lda, int ldb, int ldc,
    long sA, long sB, long sC, int relu) {
  constexpr int BM = MT * 32;
  constexpr int BN = NT * 32;
  __shared__ __align__(16) u16 As[BM * 32];
  __shared__ __align__(16) u16 Bs[BN * 32];
  const int z = blockIdx.z;
  A  += (long)z * sA;
  Bt += (long)z * sB;
  const int tid  = threadIdx.x;
  const int lane = tid & 63, wave = tid >> 6;
  const int quad = lane >> 4, l15 = lane & 15;
  const int wm = wave >> 1, wn = wave & 1;
  const u16* Ab = A  + (long)(blockIdx.y * BM) * lda;
  const u16* Bb = Bt + (long)(blockIdx.x * BN) * ldb;

  f32x4 acc[MT][NT];
#pragma unroll
  for (int i = 0; i < MT; ++i)
#pragma unroll
    for (int j = 0; j < NT; ++j) acc[i][j] = (f32x4){0.f, 0.f, 0.f, 0.f};

  const int r0  = tid >> 2;
  const int kk0 = (tid & 3) * 8;

  for (int kt = 0; kt < K; kt += 32) {
#pragma unroll
    for (int p = 0; p < BM / 64; ++p) {
      __builtin_amdgcn_global_load_lds(
          (const __attribute__((address_space(1))) void*)(Ab + (long)(p * 64 + r0) * lda + kt + kk0),
          (__attribute__((address_space(3))) void*)(&As[p * 2048 + tid * 8]), 16, 0, 0);
    }
#pragma unroll
    for (int p = 0; p < BN / 64; ++p) {
      __builtin_amdgcn_global_load_lds(
          (const __attribute__((address_space(1))) void*)(Bb + (long)(p * 64 + r0) * ldb + kt + kk0),
          (__attribute__((address_space(3))) void*)(&Bs[p * 2048 + tid * 8]), 16, 0, 0);
    }
    __syncthreads();
    short8 af[MT], bfr[NT];
#pragma unroll
    for (int mt = 0; mt < MT; ++mt)
      af[mt] = *(const short8*)&As[(wm * (MT * 16) + mt * 16 + l15) * 32 + quad * 8];
#pragma unroll
    for (int nt = 0; nt < NT; ++nt)
      bfr[nt] = *(const short8*)&Bs[(wn * (NT * 16) + nt * 16 + l15) * 32 + quad * 8];
#pragma unroll
    for (int mt = 0; mt < MT; ++mt)
#pragma unroll
      for (int nt = 0; nt < NT; ++nt)
        acc[mt][nt] = __builtin_amdgcn_mfma_f32_16x16x32_bf16(af[mt], bfr[nt], acc[mt][nt], 0, 0, 0);
    __syncthreads();
  }

#pragma unroll
  for (int nt = 0; nt < NT; ++nt) {
    const int col = blockIdx.x * BN + wn * (NT * 16) + nt * 16 + l15;
    const float bvv = bias ? bias[col] : 0.f;
#pragma unroll
    for (int mt = 0; mt < MT; ++mt) {
#pragma unroll
      for (int r = 0; r < 4; ++r) {
        const int row = blockIdx.y * BM + wm * (MT * 16) + mt * 16 + quad * 4 + r;
        float v = acc[mt][nt][r] + bvv;
        if (relu) v = fmaxf(v, 0.f);
        if (OUTF32) ((float*)Cv)[(long)z * sC + (long)row * ldc + col] = v;
        else        ((u16*)Cv)[(long)z * sC + (long)row * ldc + col] = f2bf(v);
      }
    }
  }
}

// ---------------- QKV batched GEMM: z=0: Q=x@Wq, z=1: K=y@Wk, z=2: V=y@Wv ---------
__global__ __launch_bounds__(256) void qkv_k(
    const u16* __restrict__ xb, const u16* __restrict__ yb,
    const u16* __restrict__ WqT, const u16* __restrict__ WkT, const u16* __restrict__ WvT,
    const float* __restrict__ bq, const float* __restrict__ bk, const float* __restrict__ bv,
    u16* __restrict__ Q, u16* __restrict__ Kp, u16* __restrict__ Vp) {
  __shared__ __align__(16) u16 As[128 * 32];
  __shared__ __align__(16) u16 Bs[128 * 32];
  const int z = blockIdx.z;
  const u16* A  = (z == 0) ? xb : yb;
  const u16* Bt = (z == 0) ? WqT : (z == 1) ? WkT : WvT;
  const float* bias = (z == 0) ? bq : (z == 1) ? bk : bv;
  u16* C = (z == 0) ? Q : (z == 1) ? Kp : Vp;
  const int tid  = threadIdx.x;
  const int lane = tid & 63, wave = tid >> 6;
  const int quad = lane >> 4, l15 = lane & 15;
  const int wm = wave >> 1, wn = wave & 1;
  const u16* Ab = A  + (long)(blockIdx.y * 128) * D_;
  const u16* Bb = Bt + (long)(blockIdx.x * 128) * D_;

  f32x4 acc[4][4];
#pragma unroll
  for (int i = 0; i < 4; ++i)
#pragma unroll
    for (int j = 0; j < 4; ++j) acc[i][j] = (f32x4){0.f, 0.f, 0.f, 0.f};

  const int r0  = tid >> 2;
  const int kk0 = (tid & 3) * 8;

  for (int kt = 0; kt < D_; kt += 32) {
#pragma unroll
    for (int p = 0; p < 2; ++p) {
      __builtin_amdgcn_global_load_lds(
          (const __attribute__((address_space(1))) void*)(Ab + (long)(p * 64 + r0) * D_ + kt + kk0),
          (__attribute__((address_space(3))) void*)(&As[p * 2048 + tid * 8]), 16, 0, 0);
      __builtin_amdgcn_global_load_lds(
          (const __attribute__((address_space(1))) void*)(Bb + (long)(p * 64 + r0) * D_ + kt + kk0),
          (__attribute__((address_space(3))) void*)(&Bs[p * 2048 + tid * 8]), 16, 0, 0);
    }
    __syncthreads();
    short8 af[4], bfr[4];
#pragma unroll
    for (int mt = 0; mt < 4; ++mt)
      af[mt] = *(const short8*)&As[(wm * 64 + mt * 16 + l15) * 32 + quad * 8];
#pragma unroll
    for (int nt = 0; nt < 4; ++nt)
      bfr[nt] = *(const short8*)&Bs[(wn * 64 + nt * 16 + l15) * 32 + quad * 8];
#pragma unroll
    for (int mt = 0; mt < 4; ++mt)
#pragma unroll
      for (int nt = 0; nt < 4; ++nt)
        acc[mt][nt] = __builtin_amdgcn_mfma_f32_16x16x32_bf16(af[mt], bfr[nt], acc[mt][nt], 0, 0, 0);
    __syncthreads();
  }

#pragma unroll
  for (int nt = 0; nt < 4; ++nt) {
    const int col = blockIdx.x * 128 + wn * 64 + nt * 16 + l15;
    const float bvv = bias[col];
#pragma unroll
    for (int mt = 0; mt < 4; ++mt) {
#pragma unroll
      for (int r = 0; r < 4; ++r) {
        const int row = blockIdx.y * 128 + wm * 64 + mt * 16 + quad * 4 + r;
        C[(long)row * D_ + col] = f2bf(acc[mt][nt][r] + bvv);
      }
    }
  }
}

// ---------------- transpose + convert: out_bf16[C,R] = in_f32[R,C] ----------------
__global__ void transpose_k(const float* __restrict__ in, u16* __restrict__ outp, int R, int Ccols) {
  __shared__ u16 tile[32][33];
  const int c0 = blockIdx.x * 32, r0 = blockIdx.y * 32;
  const int tx = threadIdx.x, ty = threadIdx.y;
  for (int i = ty; i < 32; i += 8)
    tile[i][tx] = f2bf(in[(long)(r0 + i) * Ccols + c0 + tx]);
  __syncthreads();
  for (int i = ty; i < 32; i += 8)
    outp[(long)(c0 + i) * R + r0 + tx] = tile[tx][i];
}

// ---------------- V[b,s,h*64+d] -> Vt[bh][d][s]  (bf16 in/out) ----------------
__global__ void vtrans_k(const u16* __restrict__ V, u16* __restrict__ Vt) {
  __shared__ u16 tile[32][33];
  const int bh = blockIdx.z, b = bh >> 4, h = bh & 15;
  const u16* in = V + (long)b * S_ * D_ + h * DK_;
  u16* outp = Vt + (long)bh * DK_ * S_;
  const int s0 = blockIdx.x * 32, d0 = blockIdx.y * 32;
  const int tx = threadIdx.x, ty = threadIdx.y;
  for (int i = ty; i < 32; i += 8)
    tile[i][tx] = in[(long)(s0 + i) * D_ + d0 + tx];
  __syncthreads();
  for (int i = ty; i < 32; i += 8)
    outp[(long)(d0 + i) * S_ + s0 + tx] = tile[tx][i];
}

// ---------------- fused flash attention ----------------
// grid (S/256, B*H), 512 threads (8 waves). Each block: 256 q-rows of one (b,h).
// Wave w owns q-rows [w*32, w*32+32). Sc^T = K@Q^T per 128-kv tile (stats wave-local),
// P=exp(Sc/8+maskbias) (no max-sub: scores are O(1), clamp at 30), P->LDS, O+=P@V.
#define FA_LDS 151552
__global__ __launch_bounds__(512, 2) void flash_k(
    const u16* __restrict__ Q, const u16* __restrict__ Kp, const u16* __restrict__ Vt,
    const int* __restrict__ mask, u16* __restrict__ ctx) {
  extern __shared__ __align__(16) char smem[];
  u16*   sQ    = (u16*)(smem);             // [256][72]  36864 B
  u16*   sK    = (u16*)(smem + 36864);     // [128][72]  18432 B
  u16*   sV    = (u16*)(smem + 55296);     // [64][136]  17408 B
  u16*   sP    = (u16*)(smem + 72704);     // [256][136] 69632 B
  float* sBias = (float*)(smem + 142336);  // [2048]      8192 B
  float* sL    = (float*)(smem + 150528);  // [256]       1024 B

  const int qt = blockIdx.x, bh = blockIdx.y;
  const int b = bh >> 4, h = bh & 15;
  const int qbase = qt * 256;
  const int tid = threadIdx.x;
  const int w = tid >> 6, lane = tid & 63;
  const int quad = lane >> 4, l15 = lane & 15;

  const u16* Qg  = Q  + ((long)b * S_ + qbase) * D_ + h * DK_;
  const u16* Kg  = Kp + (long)b * S_ * D_ + h * DK_;
  const u16* Vtg = Vt + (long)bh * DK_ * S_;
  u16* ctxg = ctx + ((long)b * S_ + qbase) * D_ + h * DK_;

  // ---- stage Q (once) ----
#pragma unroll
  for (int p = 0; p < 4; ++p) {
    const int idx = p * 512 + tid;
    const int row = idx >> 3, cb = idx & 7;
    uint4 v = *(const uint4*)(Qg + (long)row * D_ + cb * 8);
    *(uint4*)&sQ[row * 72 + cb * 8] = v;
  }
  // ---- stage mask bias (once) ----
  {
    int4 mv = ((const int4*)(mask + (long)b * S_))[tid];
    sBias[tid * 4 + 0] = mv.x ? 0.f : -1e30f;
    sBias[tid * 4 + 1] = mv.y ? 0.f : -1e30f;
    sBias[tid * 4 + 2] = mv.z ? 0.f : -1e30f;
    sBias[tid * 4 + 3] = mv.w ? 0.f : -1e30f;
  }

  uint4 kreg[2], vreg[2];
  const int krow = tid >> 3, kcb = tid & 7;   // K stage: 128 rows x 64 cols
  const int vd = tid >> 4, vcb = tid & 15;    // V stage: 64 rows x 128 cols
  // preload tile 0
#pragma unroll
  for (int p = 0; p < 2; ++p) {
    kreg[p] = *(const uint4*)(Kg  + (long)(p * 64 + krow) * D_ + kcb * 8);
    vreg[p] = *(const uint4*)(Vtg + (long)(p * 32 + vd) * S_ + vcb * 8);
  }

  float lsum[2] = {0.f, 0.f};
  f32x4 accO[2][4];
#pragma unroll
  for (int i = 0; i < 2; ++i)
#pragma unroll
    for (int j = 0; j < 4; ++j) accO[i][j] = (f32x4){0.f, 0.f, 0.f, 0.f};

  for (int t = 0; t < 16; ++t) {
    // ---- write staged regs to LDS ----
#pragma unroll
    for (int p = 0; p < 2; ++p) {
      *(uint4*)&sK[(p * 64 + krow) * 72 + kcb * 8] = kreg[p];
      *(uint4*)&sV[(p * 32 + vd) * 136 + vcb * 8] = vreg[p];
    }
    __syncthreads();
    // ---- prefetch next tile ----
    if (t < 15) {
      const int kb2 = (t + 1) * 128;
#pragma unroll
      for (int p = 0; p < 2; ++p) {
        kreg[p] = *(const uint4*)(Kg  + (long)(kb2 + p * 64 + krow) * D_ + kcb * 8);
        vreg[p] = *(const uint4*)(Vtg + (long)(p * 32 + vd) * S_ + kb2 + vcb * 8);
      }
    }
    // ---- scores: Sc^T[kpos][q] = sum_d K[kpos][d] * Q[q][d] ----
    f32x4 accS[8][2];
#pragma unroll
    for (int i = 0; i < 8; ++i)
#pragma unroll
      for (int j = 0; j < 2; ++j) accS[i][j] = (f32x4){0.f, 0.f, 0.f, 0.f};
#pragma unroll
    for (int kt = 0; kt < 2; ++kt) {
      short8 kf[8], qf[2];
#pragma unroll
      for (int mt = 0; mt < 8; ++mt)
        kf[mt] = *(const short8*)&sK[(mt * 16 + l15) * 72 + kt * 32 + quad * 8];
#pragma unroll
      for (int nt = 0; nt < 2; ++nt)
        qf[nt] = *(const short8*)&sQ[(w * 32 + nt * 16 + l15) * 72 + kt * 32 + quad * 8];
#pragma unroll
      for (int mt = 0; mt < 8; ++mt)
#pragma unroll
        for (int nt = 0; nt < 2; ++nt)
          accS[mt][nt] = __builtin_amdgcn_mfma_f32_16x16x32_bf16(kf[mt], qf[nt], accS[mt][nt], 0, 0, 0);
    }
    // ---- bias + exp + P write ----
#pragma unroll
    for (int mt = 0; mt < 8; ++mt) {
      const f32x4 b4 = *(const f32x4*)&sBias[t * 128 + mt * 16 + quad * 4];
#pragma unroll
      for (int nt = 0; nt < 2; ++nt) {
#pragma unroll
        for (int r = 0; r < 4; ++r) {
          float s = accS[mt][nt][r] * 0.125f + b4[r];
          s = fminf(s, 30.f);
          const float p = __expf(s);
          accS[mt][nt][r] = p;
          lsum[nt] += p;
        }
        const int q = w * 32 + nt * 16 + l15;
        ushort4 pk;
        pk.x = f2bf(accS[mt][nt][0]); pk.y = f2bf(accS[mt][nt][1]);
        pk.z = f2bf(accS[mt][nt][2]); pk.w = f2bf(accS[mt][nt][3]);
        *(ushort4*)&sP[q * 136 + mt * 16 + quad * 4] = pk;
      }
    }
    // ---- PV: O[q][d] += P[q][kpos] * V[kpos][d] ----
#pragma unroll
    for (int kt = 0; kt < 4; ++kt) {
      short8 pf[2], vf[4];
#pragma unroll
      for (int mt = 0; mt < 2; ++mt)
        pf[mt] = *(const short8*)&sP[(w * 32 + mt * 16 + l15) * 136 + kt * 32 + quad * 8];
#pragma unroll
      for (int nt = 0; nt < 4; ++nt)
        vf[nt] = *(const short8*)&sV[(nt * 16 + l15) * 136 + kt * 32 + quad * 8];
#pragma unroll
      for (int mt = 0; mt < 2; ++mt)
#pragma unroll
        for (int nt = 0; nt < 4; ++nt)
          accO[mt][nt] = __builtin_amdgcn_mfma_f32_16x16x32_bf16(pf[mt], vf[nt], accO[mt][nt], 0, 0, 0);
    }
    __syncthreads();
  }

  // ---- epilogue: normalize by l, store ----
#pragma unroll
  for (int nt = 0; nt < 2; ++nt) {
    float l = lsum[nt];
    l += __shfl_xor(l, 16, 64);
    l += __shfl_xor(l, 32, 64);
    if (quad == 0) sL[w * 32 + nt * 16 + l15] = l;
  }
#pragma unroll
  for (int mt = 0; mt < 2; ++mt) {
    const f32x4 rl = *(const f32x4*)&sL[w * 32 + mt * 16 + quad * 4];
#pragma unroll
    for (int nt = 0; nt < 4; ++nt) {
#pragma unroll
      for (int r = 0; r < 4; ++r) {
        const float o = accO[mt][nt][r] / rl[r];
        ctxg[(long)(w * 32 + mt * 16 + quad * 4 + r) * D_ + nt * 16 + l15] = f2bf(o);
      }
    }
  }
}

// ---------------- add + layernorm helpers ----------------
__device__ __forceinline__ float block_reduce_sum(float v, float* red) {
#pragma unroll
  for (int off = 32; off; off >>= 1) v += __shfl_down(v, off, 64);
  __syncthreads();
  if ((threadIdx.x & 63) == 0) red[threadIdx.x >> 6] = v;
  __syncthreads();
  return red[0] + red[1] + red[2] + red[3];
}

// x (fp32) + mha (bf16) -> LN -> x1 (bf16)
__global__ __launch_bounds__(256) void addln_fb(const float* __restrict__ A, const u16* __restrict__ Bres,
    const float* __restrict__ g, const float* __restrict__ be, u16* __restrict__ outp) {
  __shared__ float red[4];
  const int row = blockIdx.x, tid = threadIdx.x;
  const float4 av = ((const float4*)(A + (long)row * D_))[tid];
  const uint2 bv2 = ((const uint2*)(Bres + (long)row * D_))[tid];
  float xv[4];
  xv[0] = av.x + bf2f((u16)(bv2.x & 0xffff));
  xv[1] = av.y + bf2f((u16)(bv2.x >> 16));
  xv[2] = av.z + bf2f((u16)(bv2.y & 0xffff));
  xv[3] = av.w + bf2f((u16)(bv2.y >> 16));
  float s  = xv[0] + xv[1] + xv[2] + xv[3];
  float ss = xv[0]*xv[0] + xv[1]*xv[1] + xv[2]*xv[2] + xv[3]*xv[3];
  s  = block_reduce_sum(s, red);
  ss = block_reduce_sum(ss, red);
  const float m   = s * (1.0f / 1024.0f);
  const float var = ss * (1.0f / 1024.0f) - m * m;
  const float rs  = rsqrtf(var + 1e-5f);
  const int c0 = tid * 4;
  float v0 = (xv[0] - m) * rs * g[c0 + 0] + be[c0 + 0];
  float v1 = (xv[1] - m) * rs * g[c0 + 1] + be[c0 + 1];
  float v2 = (xv[2] - m) * rs * g[c0 + 2] + be[c0 + 2];
  float v3 = (xv[3] - m) * rs * g[c0 + 3] + be[c0 + 3];
  unsigned int o01 = (unsigned int)f2bf(v0) | ((unsigned int)f2bf(v1) << 16);
  unsigned int o23 = (unsigned int)f2bf(v2) | ((unsigned int)f2bf(v3) << 16);
  ((uint2*)(outp + (long)row * D_))[tid] = make_uint2(o01, o23);
}

// x1 (bf16) + p0 + p1 (fp32 split-K partials) + b2 -> LN -> out (fp32)
__global__ __launch_bounds__(256) void addln2_bf(const u16* __restrict__ A,
    const float* __restrict__ p0, const float* __restrict__ p1, const float* __restrict__ b2,
    const float* __restrict__ g, const float* __restrict__ be, float* __restrict__ outp) {
  __shared__ float red[4];
  const int row = blockIdx.x, tid = threadIdx.x;
  const uint2 av  = ((const uint2*)(A + (long)row * D_))[tid];
  const float4 P0 = ((const float4*)(p0 + (long)row * D_))[tid];
  const float4 P1 = ((const float4*)(p1 + (long)row * D_))[tid];
  const int c0 = tid * 4;
  float xv[4];
  xv[0] = bf2f((u16)(av.x & 0xffff)) + P0.x + P1.x + b2[c0 + 0];
  xv[1] = bf2f((u16)(av.x >> 16))    + P0.y + P1.y + b2[c0 + 1];
  xv[2] = bf2f((u16)(av.y & 0xffff)) + P0.z + P1.z + b2[c0 + 2];
  xv[3] = bf2f((u16)(av.y >> 16))    + P0.w + P1.w + b2[c0 + 3];
  float s  = xv[0] + xv[1] + xv[2] + xv[3];
  float ss = xv[0]*xv[0] + xv[1]*xv[1] + xv[2]*xv[2] + xv[3]*xv[3];
  s  = block_reduce_sum(s, red);
  ss = block_reduce_sum(ss, red);
  const float m   = s * (1.0f / 1024.0f);
  const float var = ss * (1.0f / 1024.0f) - m * m;
  const float rs  = rsqrtf(var + 1e-5f);
  float4 o;
  o.x = (xv[0] - m) * rs * g[c0 + 0] + be[c0 + 0];
  o.y = (xv[1] - m) * rs * g[c0 + 1] + be[c0 + 1];
  o.z = (xv[2] - m) * rs * g[c0 + 2] + be[c0 + 2];
  o.w = (xv[3] - m) * rs * g[c0 + 3] + be[c0 + 3];
  ((float4*)(outp + (long)row * D_))[tid] = o;
}

extern "C" void kernel_launch(void* const* d_in, const int* in_sizes, int n_in,
                              void* d_out, int out_size, void* d_ws, size_t ws_size,
                              hipStream_t stream) {
  const float* x   = (const float*)d_in[0];
  const float* y   = (const float*)d_in[1];
  const int* mask  = (const int*)d_in[2];
  const float* Wq = (const float*)d_in[3];  const float* bq = (const float*)d_in[4];
  const float* Wk = (const float*)d_in[5];  const float* bk = (const float*)d_in[6];
  const float* Wv = (const float*)d_in[7];  const float* bv = (const float*)d_in[8];
  const float* Wo = (const float*)d_in[9];  const float* bo = (const float*)d_in[10];
  const float* W1 = (const float*)d_in[11]; const float* b1 = (const float*)d_in[12];
  const float* W2 = (const float*)d_in[13]; const float* b2 = (const float*)d_in[14];
  const float* g1 = (const float*)d_in[15]; const float* be1 = (const float*)d_in[16];
  const float* g2 = (const float*)d_in[17]; const float* be2 = (const float*)d_in[18];
  float* out = (float*)d_out;

  char* w = (char*)d_ws;
  const size_t MB = 1024 * 1024;
  u16* WqT = (u16*)(w + 0 * MB);
  u16* WkT = (u16*)(w + 2 * MB);
  u16* WvT = (u16*)(w + 4 * MB);
  u16* WoT = (u16*)(w + 6 * MB);
  u16* W1T = (u16*)(w + 8 * MB);     // 8MB [HID][D]
  u16* W2T = (u16*)(w + 16 * MB);    // 8MB [D][HID]
  u16* xb  = (u16*)(w + 24 * MB);
  u16* yb  = (u16*)(w + 32 * MB);
  u16* Q   = (u16*)(w + 40 * MB);    // dead after flash
  u16* Kp  = (u16*)(w + 48 * MB);    // dead after flash
  u16* Vp  = (u16*)(w + 56 * MB);    // dead after vtrans
  u16* Vt  = (u16*)(w + 64 * MB);    // dead after flash
  u16* ctx = (u16*)(w + 72 * MB);
  u16* mha = (u16*)(w + 80 * MB);
  u16* x1  = (u16*)(w + 88 * MB);
  u16* h1  = (u16*)(w + 96 * MB);    // 32MB bf16 [4096][4096]
  float* pK = (float*)(w + 40 * MB); // 32MB: 2x fp32 [4096][1024] split-K partials (reuses Q/Kp/Vp/Vt)

  static int shmem_set = 0;
  hipFuncSetAttribute((const void*)flash_k, hipFuncAttributeMaxDynamicSharedMemorySize, FA_LDS);
  (void)shmem_set;

  dim3 t328(32, 8);
  transpose_k<<<dim3(32, 32), t328, 0, stream>>>(Wq, WqT, 1024, 1024);
  transpose_k<<<dim3(32, 32), t328, 0, stream>>>(Wk, WkT, 1024, 1024);
  transpose_k<<<dim3(32, 32), t328, 0, stream>>>(Wv, WvT, 1024, 1024);
  transpose_k<<<dim3(32, 32), t328, 0, stream>>>(Wo, WoT, 1024, 1024);
  transpose_k<<<dim3(128, 32), t328, 0, stream>>>(W1, W1T, 1024, 4096);
  transpose_k<<<dim3(32, 128), t328, 0, stream>>>(W2, W2T, 4096, 1024);
  cvt_f2b<<<dim3(4096), 256, 0, stream>>>(x, xb);
  cvt_f2b<<<dim3(4096), 256, 0, stream>>>(y, yb);

  // QKV: one dispatch, 768 blocks
  qkv_k<<<dim3(8, 32, 3), 256, 0, stream>>>(xb, yb, WqT, WkT, WvT, bq, bk, bv, Q, Kp, Vp);

  vtrans_k<<<dim3(64, 2, 32), t328, 0, stream>>>(Vp, Vt);

  // fused flash attention: 256 blocks x 8 waves
  flash_k<<<dim3(8, 32), 512, FA_LDS, stream>>>(Q, Kp, Vt, mask, ctx);

  // output projection (<2,4>: 512 blocks) + LN1
  gemm_bt<2, 4, 0><<<dim3(8, 64, 1), 256, 0, stream>>>(ctx, WoT, bo, mha,
      1024, 1024, 1024, 1024, 0, 0, 0, 0);
  addln_fb<<<dim3(4096), 256, 0, stream>>>(x, mha, g1, be1, x1);

  // FFN1: 1024 blocks
  gemm_bt<4, 4, 0><<<dim3(32, 32, 1), 256, 0, stream>>>(x1, W1T, b1, h1,
      1024, 1024, 1024, 4096, 0, 0, 0, 1);
  // FFN2: split-K=2, fp32 partials, 512 blocks
  gemm_bt<4, 4, 1><<<dim3(8, 32, 2), 256, 0, stream>>>(h1, W2T, nullptr, (void*)pK,
      2048, 4096, 4096, 1024, 2048, 2048, (long)4096 * 1024, 0);
  // combine partials + bias + residual + LN2 -> out
  addln2_bf<<<dim3(4096), 256, 0, stream>>>(x1, pK, pK + (long)4096 * 1024, b2, g2, be2, out);
}

// Round 4
// 467.723 us; speedup vs baseline: 1.5915x; 1.0098x over previous
//
#include <hip/hip_runtime.h>

#define S_ 2048
#define D_ 1024
#define B_ 2
#define H_ 16
#define DK_ 64
#define HID_ 4096

typedef unsigned short u16;
typedef __attribute__((ext_vector_type(8))) short short8;
typedef __attribute__((ext_vector_type(4))) float f32x4;

__device__ __forceinline__ float bf2f(u16 u) {
  return __uint_as_float(((unsigned int)u) << 16);
}
__device__ __forceinline__ u16 f2bf(float f) {
  unsigned int x = __float_as_uint(f);
  x += 0x7fff + ((x >> 16) & 1);
  return (u16)(x >> 16);
}
// fast pack two floats -> bf16x2 (round-to-nearest, no tie-to-even)
__device__ __forceinline__ unsigned int pk2bf(float lo, float hi) {
  return ((__float_as_uint(lo) + 0x8000u) >> 16) | ((__float_as_uint(hi) + 0x8000u) & 0xffff0000u);
}

// ---------------- fp32 -> bf16 convert (4 elems/thread) ----------------
__global__ __launch_bounds__(256) void cvt_f2b(const float* __restrict__ in, u16* __restrict__ outp) {
  const int i = blockIdx.x * 256 + threadIdx.x;
  float4 v = ((const float4*)in)[i];
  unsigned int lo = (unsigned int)f2bf(v.x) | ((unsigned int)f2bf(v.y) << 16);
  unsigned int hi = (unsigned int)f2bf(v.z) | ((unsigned int)f2bf(v.w) << 16);
  ((uint2*)outp)[i] = make_uint2(lo, hi);
}

// ---------------- mask -> additive bias in log2 domain ----------------
__global__ __launch_bounds__(256) void maskbias_k(const int* __restrict__ mask, float* __restrict__ biasf) {
  const int i = blockIdx.x * 256 + threadIdx.x;
  biasf[i] = mask[i] ? 0.f : -1e30f;
}

// ---------------- generic bf16 GEMM: C[M,N] = A[M,K] @ Bt[N,K]^T ----------------
template<int MT, int NT, int OUTF32>
__global__ __launch_bounds__(256) void gemm_bt(
    const u16* __restrict__ A, const u16* __restrict__ Bt,
    const float* __restrict__ bias, void* __restrict__ Cv,
    int K, int lda, int ldb, int ldc,
    long sA, long sB, long sC, int relu) {
  constexpr int BM = MT * 32;
  constexpr int BN = NT * 32;
  __shared__ __align__(16) u16 As[BM * 32];
  __shared__ __align__(16) u16 Bs[BN * 32];
  const int z = blockIdx.z;
  A  += (long)z * sA;
  Bt += (long)z * sB;
  const int tid  = threadIdx.x;
  const int lane = tid & 63, wave = tid >> 6;
  const int quad = lane >> 4, l15 = lane & 15;
  const int wm = wave >> 1, wn = wave & 1;
  const u16* Ab = A  + (long)(blockIdx.y * BM) * lda;
  const u16* Bb = Bt + (long)(blockIdx.x * BN) * ldb;

  f32x4 acc[MT][NT];
#pragma unroll
  for (int i = 0; i < MT; ++i)
#pragma unroll
    for (int j = 0; j < NT; ++j) acc[i][j] = (f32x4){0.f, 0.f, 0.f, 0.f};

  const int r0  = tid >> 2;
  const int kk0 = (tid & 3) * 8;

  for (int kt = 0; kt < K; kt += 32) {
#pragma unroll
    for (int p = 0; p < BM / 64; ++p) {
      __builtin_amdgcn_global_load_lds(
          (const __attribute__((address_space(1))) void*)(Ab + (long)(p * 64 + r0) * lda + kt + kk0),
          (__attribute__((address_space(3))) void*)(&As[p * 2048 + tid * 8]), 16, 0, 0);
    }
#pragma unroll
    for (int p = 0; p < BN / 64; ++p) {
      __builtin_amdgcn_global_load_lds(
          (const __attribute__((address_space(1))) void*)(Bb + (long)(p * 64 + r0) * ldb + kt + kk0),
          (__attribute__((address_space(3))) void*)(&Bs[p * 2048 + tid * 8]), 16, 0, 0);
    }
    __syncthreads();
    short8 af[MT], bfr[NT];
#pragma unroll
    for (int mt = 0; mt < MT; ++mt)
      af[mt] = *(const short8*)&As[(wm * (MT * 16) + mt * 16 + l15) * 32 + quad * 8];
#pragma unroll
    for (int nt = 0; nt < NT; ++nt)
      bfr[nt] = *(const short8*)&Bs[(wn * (NT * 16) + nt * 16 + l15) * 32 + quad * 8];
#pragma unroll
    for (int mt = 0; mt < MT; ++mt)
#pragma unroll
      for (int nt = 0; nt < NT; ++nt)
        acc[mt][nt] = __builtin_amdgcn_mfma_f32_16x16x32_bf16(af[mt], bfr[nt], acc[mt][nt], 0, 0, 0);
    __syncthreads();
  }

#pragma unroll
  for (int nt = 0; nt < NT; ++nt) {
    const int col = blockIdx.x * BN + wn * (NT * 16) + nt * 16 + l15;
    const float bvv = bias ? bias[col] : 0.f;
#pragma unroll
    for (int mt = 0; mt < MT; ++mt) {
#pragma unroll
      for (int r = 0; r < 4; ++r) {
        const int row = blockIdx.y * BM + wm * (MT * 16) + mt * 16 + quad * 4 + r;
        float v = acc[mt][nt][r] + bvv;
        if (relu) v = fmaxf(v, 0.f);
        if (OUTF32) ((float*)Cv)[(long)z * sC + (long)row * ldc + col] = v;
        else        ((u16*)Cv)[(long)z * sC + (long)row * ldc + col] = f2bf(v);
      }
    }
  }
}

// ---------------- QKV batched GEMM (Q pre-scaled by 0.125*log2e) -------------
__global__ __launch_bounds__(256) void qkv_k(
    const u16* __restrict__ xb, const u16* __restrict__ yb,
    const u16* __restrict__ WqT, const u16* __restrict__ WkT, const u16* __restrict__ WvT,
    const float* __restrict__ bq, const float* __restrict__ bk, const float* __restrict__ bv,
    u16* __restrict__ Q, u16* __restrict__ Kp, u16* __restrict__ Vp) {
  __shared__ __align__(16) u16 As[128 * 32];
  __shared__ __align__(16) u16 Bs[128 * 32];
  const int z = blockIdx.z;
  const u16* A  = (z == 0) ? xb : yb;
  const u16* Bt = (z == 0) ? WqT : (z == 1) ? WkT : WvT;
  const float* bias = (z == 0) ? bq : (z == 1) ? bk : bv;
  u16* C = (z == 0) ? Q : (z == 1) ? Kp : Vp;
  const float sc = (z == 0) ? 0.18033688011112042f : 1.0f;  // 0.125*log2(e) for Q
  const int tid  = threadIdx.x;
  const int lane = tid & 63, wave = tid >> 6;
  const int quad = lane >> 4, l15 = lane & 15;
  const int wm = wave >> 1, wn = wave & 1;
  const u16* Ab = A  + (long)(blockIdx.y * 128) * D_;
  const u16* Bb = Bt + (long)(blockIdx.x * 128) * D_;

  f32x4 acc[4][4];
#pragma unroll
  for (int i = 0; i < 4; ++i)
#pragma unroll
    for (int j = 0; j < 4; ++j) acc[i][j] = (f32x4){0.f, 0.f, 0.f, 0.f};

  const int r0  = tid >> 2;
  const int kk0 = (tid & 3) * 8;

  for (int kt = 0; kt < D_; kt += 32) {
#pragma unroll
    for (int p = 0; p < 2; ++p) {
      __builtin_amdgcn_global_load_lds(
          (const __attribute__((address_space(1))) void*)(Ab + (long)(p * 64 + r0) * D_ + kt + kk0),
          (__attribute__((address_space(3))) void*)(&As[p * 2048 + tid * 8]), 16, 0, 0);
      __builtin_amdgcn_global_load_lds(
          (const __attribute__((address_space(1))) void*)(Bb + (long)(p * 64 + r0) * D_ + kt + kk0),
          (__attribute__((address_space(3))) void*)(&Bs[p * 2048 + tid * 8]), 16, 0, 0);
    }
    __syncthreads();
    short8 af[4], bfr[4];
#pragma unroll
    for (int mt = 0; mt < 4; ++mt)
      af[mt] = *(const short8*)&As[(wm * 64 + mt * 16 + l15) * 32 + quad * 8];
#pragma unroll
    for (int nt = 0; nt < 4; ++nt)
      bfr[nt] = *(const short8*)&Bs[(wn * 64 + nt * 16 + l15) * 32 + quad * 8];
#pragma unroll
    for (int mt = 0; mt < 4; ++mt)
#pragma unroll
      for (int nt = 0; nt < 4; ++nt)
        acc[mt][nt] = __builtin_amdgcn_mfma_f32_16x16x32_bf16(af[mt], bfr[nt], acc[mt][nt], 0, 0, 0);
    __syncthreads();
  }

#pragma unroll
  for (int nt = 0; nt < 4; ++nt) {
    const int col = blockIdx.x * 128 + wn * 64 + nt * 16 + l15;
    const float bvv = bias[col];
#pragma unroll
    for (int mt = 0; mt < 4; ++mt) {
#pragma unroll
      for (int r = 0; r < 4; ++r) {
        const int row = blockIdx.y * 128 + wm * 64 + mt * 16 + quad * 4 + r;
        C[(long)row * D_ + col] = f2bf((acc[mt][nt][r] + bvv) * sc);
      }
    }
  }
}

// ---------------- transpose + convert: out_bf16[C,R] = in_f32[R,C] ----------------
__global__ void transpose_k(const float* __restrict__ in, u16* __restrict__ outp, int R, int Ccols) {
  __shared__ u16 tile[32][33];
  const int c0 = blockIdx.x * 32, r0 = blockIdx.y * 32;
  const int tx = threadIdx.x, ty = threadIdx.y;
  for (int i = ty; i < 32; i += 8)
    tile[i][tx] = f2bf(in[(long)(r0 + i) * Ccols + c0 + tx]);
  __syncthreads();
  for (int i = ty; i < 32; i += 8)
    outp[(long)(c0 + i) * R + r0 + tx] = tile[tx][i];
}

// ---------------- V[b,s,h*64+d] -> Vt[bh][d][s]  (bf16 in/out) ----------------
__global__ void vtrans_k(const u16* __restrict__ V, u16* __restrict__ Vt) {
  __shared__ u16 tile[32][33];
  const int bh = blockIdx.z, b = bh >> 4, h = bh & 15;
  const u16* in = V + (long)b * S_ * D_ + h * DK_;
  u16* outp = Vt + (long)bh * DK_ * S_;
  const int s0 = blockIdx.x * 32, d0 = blockIdx.y * 32;
  const int tx = threadIdx.x, ty = threadIdx.y;
  for (int i = ty; i < 32; i += 8)
    tile[i][tx] = in[(long)(s0 + i) * D_ + d0 + tx];
  __syncthreads();
  for (int i = ty; i < 32; i += 8)
    outp[(long)(d0 + i) * S_ + s0 + tx] = tile[tx][i];
}

// ---------------- fused flash attention v2 ----------------
// grid (B*H, S/256), 256 threads (4 waves). Wave w owns q in [w*64, w*64+64).
// kv tiles of 32, 64 iterations, K/V LDS double-buffered, Q frags persistent
// in registers. All LDS in 32-col panels (m97 contiguity). sP XOR-swizzled.
// Q pre-scaled by 0.125*log2e -> P = exp2(s + maskbias).
#define FA_LDS 65536
__global__ __launch_bounds__(256, 2) void flash_k(
    const u16* __restrict__ Q, const u16* __restrict__ Kp, const u16* __restrict__ Vt,
    const float* __restrict__ biasf, u16* __restrict__ ctx) {
  extern __shared__ __align__(16) char smem[];
  u16* sQ = (u16*)smem;                 // [2 d-panels][256 q][32]   32768 B
  u16* sK = (u16*)(smem + 32768);       // [2 buf][2 d-panels][32 kv][32]  8192 B
  u16* sV = (u16*)(smem + 40960);       // [2 buf][64 d][32 kv]      8192 B
  u16* sP = (u16*)(smem + 49152);       // [256 q][32 kv] swizzled  16384 B

  const int bh = blockIdx.x, qt = blockIdx.y;
  const int b = bh >> 4, h = bh & 15;
  const int tid = threadIdx.x;
  const int w = tid >> 6, lane = tid & 63;
  const int quad = lane >> 4, l15 = lane & 15;
  const int swz = ((l15 ^ (l15 >> 2)) & 3) << 3;

  const u16* Qg  = Q  + ((long)b * S_ + qt * 256) * D_ + h * DK_;
  const u16* Kg  = Kp + (long)b * S_ * D_ + h * DK_;
  const u16* Vtg = Vt + (long)bh * DK_ * S_;
  const float* biasg = biasf + b * S_;
  u16* ctxg = ctx + ((long)b * S_ + qt * 256) * D_ + h * DK_;

  // staging maps
  const int krow = tid >> 3, kc = tid & 7;            // K: 32 rows x 4 thr... 8 thr/row
  const u16* kptr = Kg + (long)krow * D_ + kc * 8;
  const int ksw = ((kc >> 2) << 10) + krow * 32 + (kc & 3) * 8;
  const int vrow = tid >> 2, vc = tid & 3;            // V: 64 rows x 4 thr/row
  const u16* vptr = Vtg + (long)vrow * S_ + vc * 8;
  const int vsw = vrow * 32 + vc * 8;

  uint4 kreg = *(const uint4*)kptr;
  uint4 vreg = *(const uint4*)vptr;

  // stage Q (once)
#pragma unroll
  for (int p = 0; p < 8; ++p) {
    const int idx = p * 256 + tid;
    const int row = idx >> 3, cb = idx & 7;
    uint4 v = *(const uint4*)(Qg + (long)row * D_ + cb * 8);
    *(uint4*)&sQ[(cb >> 2) * 8192 + row * 32 + (cb & 3) * 8] = v;
  }
  *(uint4*)&sK[ksw] = kreg;
  *(uint4*)&sV[vsw] = vreg;
  kreg = *(const uint4*)(kptr + 32 * D_);
  vreg = *(const uint4*)(vptr + 32);
  kptr += 64 * D_;
  vptr += 64;
  __syncthreads();

  // persistent Q fragments
  short8 qf[4][2];
#pragma unroll
  for (int nt = 0; nt < 4; ++nt)
#pragma unroll
    for (int kt = 0; kt < 2; ++kt)
      qf[nt][kt] = *(const short8*)&sQ[kt * 8192 + (w * 64 + nt * 16 + l15) * 32 + quad * 8];

  float lsum[4] = {0.f, 0.f, 0.f, 0.f};
  f32x4 accO[4][4];
#pragma unroll
  for (int i = 0; i < 4; ++i)
#pragma unroll
    for (int j = 0; j < 4; ++j) accO[i][j] = (f32x4){0.f, 0.f, 0.f, 0.f};

  for (int t = 0; t < 64; ++t) {
    if (t) __syncthreads();
    const int buf = (t & 1) << 11;            // elems: 2048 per buf
    const int nbuf = buf ^ 2048;
    if (t < 63) {
      *(uint4*)&sK[nbuf + ksw] = kreg;
      *(uint4*)&sV[nbuf + vsw] = vreg;
      if (t < 62) {
        kreg = *(const uint4*)kptr;
        vreg = *(const uint4*)vptr;
        kptr += 32 * D_;
        vptr += 32;
      }
    }
    float4 bv0 = *(const float4*)(biasg + t * 32 + quad * 4);
    float4 bv1 = *(const float4*)(biasg + t * 32 + 16 + quad * 4);

    // scores: Sc^T[kv 32][q 64]
    f32x4 accS[2][4];
#pragma unroll
    for (int i = 0; i < 2; ++i)
#pragma unroll
      for (int j = 0; j < 4; ++j) accS[i][j] = (f32x4){0.f, 0.f, 0.f, 0.f};
#pragma unroll
    for (int kt = 0; kt < 2; ++kt) {
      short8 kf0 = *(const short8*)&sK[buf + kt * 1024 + l15 * 32 + quad * 8];
      short8 kf1 = *(const short8*)&sK[buf + kt * 1024 + (16 + l15) * 32 + quad * 8];
#pragma unroll
      for (int nt = 0; nt < 4; ++nt) {
        accS[0][nt] = __builtin_amdgcn_mfma_f32_16x16x32_bf16(kf0, qf[nt][kt], accS[0][nt], 0, 0, 0);
        accS[1][nt] = __builtin_amdgcn_mfma_f32_16x16x32_bf16(kf1, qf[nt][kt], accS[1][nt], 0, 0, 0);
      }
    }
    // exp2 + pack + swizzled P write (wave-private rows -> no barrier)
#pragma unroll
    for (int mt = 0; mt < 2; ++mt) {
      const float4 bv = mt ? bv1 : bv0;
      const int kvl = ((mt * 16 + quad * 4) ^ swz);
#pragma unroll
      for (int nt = 0; nt < 4; ++nt) {
        float p0 = exp2f(fminf(accS[mt][nt][0] + bv.x, 30.f));
        float p1 = exp2f(fminf(accS[mt][nt][1] + bv.y, 30.f));
        float p2 = exp2f(fminf(accS[mt][nt][2] + bv.z, 30.f));
        float p3 = exp2f(fminf(accS[mt][nt][3] + bv.w, 30.f));
        lsum[nt] += (p0 + p1) + (p2 + p3);
        *(uint2*)&sP[(w * 64 + nt * 16 + l15) * 32 + kvl] =
            make_uint2(pk2bf(p0, p1), pk2bf(p2, p3));
      }
    }
    // PV: O[q 64][d 64] += P @ V
    short8 pf[4], vf[4];
#pragma unroll
    for (int m = 0; m < 4; ++m)
      pf[m] = *(const short8*)&sP[(w * 64 + m * 16 + l15) * 32 + ((quad * 8) ^ swz)];
#pragma unroll
    for (int n = 0; n < 4; ++n)
      vf[n] = *(const short8*)&sV[buf + (n * 16 + l15) * 32 + quad * 8];
#pragma unroll
    for (int m = 0; m < 4; ++m)
#pragma unroll
      for (int n = 0; n < 4; ++n)
        accO[m][n] = __builtin_amdgcn_mfma_f32_16x16x32_bf16(pf[m], vf[n], accO[m][n], 0, 0, 0);
  }

  // epilogue: reduce l over quads, normalize, store
#pragma unroll
  for (int nt = 0; nt < 4; ++nt) {
    lsum[nt] += __shfl_xor(lsum[nt], 16, 64);
    lsum[nt] += __shfl_xor(lsum[nt], 32, 64);
  }
#pragma unroll
  for (int m = 0; m < 4; ++m) {
    float inv[4];
#pragma unroll
    for (int r = 0; r < 4; ++r)
      inv[r] = 1.f / __shfl(lsum[m], quad * 4 + r, 64);
#pragma unroll
    for (int n = 0; n < 4; ++n) {
#pragma unroll
      for (int r = 0; r < 4; ++r)
        ctxg[(long)(w * 64 + m * 16 + quad * 4 + r) * D_ + n * 16 + l15] =
            f2bf(accO[m][n][r] * inv[r]);
    }
  }
}

// ---------------- add + layernorm helpers ----------------
__device__ __forceinline__ float block_reduce_sum(float v, float* red) {
#pragma unroll
  for (int off = 32; off; off >>= 1) v += __shfl_down(v, off, 64);
  __syncthreads();
  if ((threadIdx.x & 63) == 0) red[threadIdx.x >> 6] = v;
  __syncthreads();
  return red[0] + red[1] + red[2] + red[3];
}

__global__ __launch_bounds__(256) void addln_fb(const float* __restrict__ A, const u16* __restrict__ Bres,
    const float* __restrict__ g, const float* __restrict__ be, u16* __restrict__ outp) {
  __shared__ float red[4];
  const int row = blockIdx.x, tid = threadIdx.x;
  const float4 av = ((const float4*)(A + (long)row * D_))[tid];
  const uint2 bv2 = ((const uint2*)(Bres + (long)row * D_))[tid];
  float xv[4];
  xv[0] = av.x + bf2f((u16)(bv2.x & 0xffff));
  xv[1] = av.y + bf2f((u16)(bv2.x >> 16));
  xv[2] = av.z + bf2f((u16)(bv2.y & 0xffff));
  xv[3] = av.w + bf2f((u16)(bv2.y >> 16));
  float s  = xv[0] + xv[1] + xv[2] + xv[3];
  float ss = xv[0]*xv[0] + xv[1]*xv[1] + xv[2]*xv[2] + xv[3]*xv[3];
  s  = block_reduce_sum(s, red);
  ss = block_reduce_sum(ss, red);
  const float m   = s * (1.0f / 1024.0f);
  const float var = ss * (1.0f / 1024.0f) - m * m;
  const float rs  = rsqrtf(var + 1e-5f);
  const int c0 = tid * 4;
  float v0 = (xv[0] - m) * rs * g[c0 + 0] + be[c0 + 0];
  float v1 = (xv[1] - m) * rs * g[c0 + 1] + be[c0 + 1];
  float v2 = (xv[2] - m) * rs * g[c0 + 2] + be[c0 + 2];
  float v3 = (xv[3] - m) * rs * g[c0 + 3] + be[c0 + 3];
  unsigned int o01 = (unsigned int)f2bf(v0) | ((unsigned int)f2bf(v1) << 16);
  unsigned int o23 = (unsigned int)f2bf(v2) | ((unsigned int)f2bf(v3) << 16);
  ((uint2*)(outp + (long)row * D_))[tid] = make_uint2(o01, o23);
}

__global__ __launch_bounds__(256) void addln2_bf(const u16* __restrict__ A,
    const float* __restrict__ p0, const float* __restrict__ p1, const float* __restrict__ b2,
    const float* __restrict__ g, const float* __restrict__ be, float* __restrict__ outp) {
  __shared__ float red[4];
  const int row = blockIdx.x, tid = threadIdx.x;
  const uint2 av  = ((const uint2*)(A + (long)row * D_))[tid];
  const float4 P0 = ((const float4*)(p0 + (long)row * D_))[tid];
  const float4 P1 = ((const float4*)(p1 + (long)row * D_))[tid];
  const int c0 = tid * 4;
  float xv[4];
  xv[0] = bf2f((u16)(av.x & 0xffff)) + P0.x + P1.x + b2[c0 + 0];
  xv[1] = bf2f((u16)(av.x >> 16))    + P0.y + P1.y + b2[c0 + 1];
  xv[2] = bf2f((u16)(av.y & 0xffff)) + P0.z + P1.z + b2[c0 + 2];
  xv[3] = bf2f((u16)(av.y >> 16))    + P0.w + P1.w + b2[c0 + 3];
  float s  = xv[0] + xv[1] + xv[2] + xv[3];
  float ss = xv[0]*xv[0] + xv[1]*xv[1] + xv[2]*xv[2] + xv[3]*xv[3];
  s  = block_reduce_sum(s, red);
  ss = block_reduce_sum(ss, red);
  const float m   = s * (1.0f / 1024.0f);
  const float var = ss * (1.0f / 1024.0f) - m * m;
  const float rs  = rsqrtf(var + 1e-5f);
  float4 o;
  o.x = (xv[0] - m) * rs * g[c0 + 0] + be[c0 + 0];
  o.y = (xv[1] - m) * rs * g[c0 + 1] + be[c0 + 1];
  o.z = (xv[2] - m) * rs * g[c0 + 2] + be[c0 + 2];
  o.w = (xv[3] - m) * rs * g[c0 + 3] + be[c0 + 3];
  ((float4*)(outp + (long)row * D_))[tid] = o;
}

extern "C" void kernel_launch(void* const* d_in, const int* in_sizes, int n_in,
                              void* d_out, int out_size, void* d_ws, size_t ws_size,
                              hipStream_t stream) {
  const float* x   = (const float*)d_in[0];
  const float* y   = (const float*)d_in[1];
  const int* mask  = (const int*)d_in[2];
  const float* Wq = (const float*)d_in[3];  const float* bq = (const float*)d_in[4];
  const float* Wk = (const float*)d_in[5];  const float* bk = (const float*)d_in[6];
  const float* Wv = (const float*)d_in[7];  const float* bv = (const float*)d_in[8];
  const float* Wo = (const float*)d_in[9];  const float* bo = (const float*)d_in[10];
  const float* W1 = (const float*)d_in[11]; const float* b1 = (const float*)d_in[12];
  const float* W2 = (const float*)d_in[13]; const float* b2 = (const float*)d_in[14];
  const float* g1 = (const float*)d_in[15]; const float* be1 = (const float*)d_in[16];
  const float* g2 = (const float*)d_in[17]; const float* be2 = (const float*)d_in[18];
  float* out = (float*)d_out;

  char* w = (char*)d_ws;
  const size_t MB = 1024 * 1024;
  u16* WqT = (u16*)(w + 0 * MB);
  u16* WkT = (u16*)(w + 2 * MB);
  u16* WvT = (u16*)(w + 4 * MB);
  u16* WoT = (u16*)(w + 6 * MB);
  u16* W1T = (u16*)(w + 8 * MB);     // 8MB [HID][D]
  u16* W2T = (u16*)(w + 16 * MB);    // 8MB [D][HID]
  u16* xb  = (u16*)(w + 24 * MB);
  u16* yb  = (u16*)(w + 32 * MB);
  u16* Q   = (u16*)(w + 40 * MB);
  u16* Kp  = (u16*)(w + 48 * MB);
  u16* Vp  = (u16*)(w + 56 * MB);
  u16* Vt  = (u16*)(w + 64 * MB);
  u16* ctx = (u16*)(w + 72 * MB);
  u16* mha = (u16*)(w + 80 * MB);
  u16* x1  = (u16*)(w + 88 * MB);
  u16* h1  = (u16*)(w + 96 * MB);    // 32MB bf16 [4096][4096]
  float* pK = (float*)(w + 40 * MB); // 32MB split-K partials (reuses Q/Kp/Vp/Vt)
  float* biasf = (float*)(w + 128 * MB); // 16KB

  hipFuncSetAttribute((const void*)flash_k, hipFuncAttributeMaxDynamicSharedMemorySize, FA_LDS);

  dim3 t328(32, 8);
  transpose_k<<<dim3(32, 32), t328, 0, stream>>>(Wq, WqT, 1024, 1024);
  transpose_k<<<dim3(32, 32), t328, 0, stream>>>(Wk, WkT, 1024, 1024);
  transpose_k<<<dim3(32, 32), t328, 0, stream>>>(Wv, WvT, 1024, 1024);
  transpose_k<<<dim3(32, 32), t328, 0, stream>>>(Wo, WoT, 1024, 1024);
  transpose_k<<<dim3(128, 32), t328, 0, stream>>>(W1, W1T, 1024, 4096);
  transpose_k<<<dim3(32, 128), t328, 0, stream>>>(W2, W2T, 4096, 1024);
  cvt_f2b<<<dim3(4096), 256, 0, stream>>>(x, xb);
  cvt_f2b<<<dim3(4096), 256, 0, stream>>>(y, yb);
  maskbias_k<<<dim3(16), 256, 0, stream>>>(mask, biasf);

  // QKV: one dispatch, 768 blocks (Q pre-scaled)
  qkv_k<<<dim3(8, 32, 3), 256, 0, stream>>>(xb, yb, WqT, WkT, WvT, bq, bk, bv, Q, Kp, Vp);

  vtrans_k<<<dim3(64, 2, 32), t328, 0, stream>>>(Vp, Vt);

  // fused flash attention v2: grid.x = bh (XCD locality), 256 thr, 64KB LDS
  flash_k<<<dim3(32, 8), 256, FA_LDS, stream>>>(Q, Kp, Vt, biasf, ctx);

  // output projection + LN1
  gemm_bt<2, 4, 0><<<dim3(8, 64, 1), 256, 0, stream>>>(ctx, WoT, bo, mha,
      1024, 1024, 1024, 1024, 0, 0, 0, 0);
  addln_fb<<<dim3(4096), 256, 0, stream>>>(x, mha, g1, be1, x1);

  // FFN1
  gemm_bt<4, 4, 0><<<dim3(32, 32, 1), 256, 0, stream>>>(x1, W1T, b1, h1,
      1024, 1024, 1024, 4096, 0, 0, 0, 1);
  // FFN2: split-K=2, fp32 partials
  gemm_bt<4, 4, 1><<<dim3(8, 32, 2), 256, 0, stream>>>(h1, W2T, nullptr, (void*)pK,
      2048, 4096, 4096, 1024, 2048, 2048, (long)4096 * 1024, 0);
  addln2_bf<<<dim3(4096), 256, 0, stream>>>(x1, pK, pK + (long)4096 * 1024, b2, g2, be2, out);
}

// Round 5
// 442.913 us; speedup vs baseline: 1.6807x; 1.0560x over previous
//
#include <hip/hip_runtime.h>

#define S_ 2048
#define D_ 1024
#define B_ 2
#define H_ 16
#define DK_ 64
#define HID_ 4096

typedef unsigned short u16;
typedef __attribute__((ext_vector_type(8))) short short8;
typedef __attribute__((ext_vector_type(4))) float f32x4;

__device__ __forceinline__ float bf2f(u16 u) {
  return __uint_as_float(((unsigned int)u) << 16);
}
__device__ __forceinline__ u16 f2bf(float f) {
  unsigned int x = __float_as_uint(f);
  x += 0x7fff + ((x >> 16) & 1);
  return (u16)(x >> 16);
}
__device__ __forceinline__ unsigned int pk2bf(float lo, float hi) {
  return ((__float_as_uint(lo) + 0x8000u) >> 16) | ((__float_as_uint(hi) + 0x8000u) & 0xffff0000u);
}

// ---------------- fused prep: 6 weight transposes (f32->bf16) + x/y cvt ------
// grid (128, 32, 8), block (32, 8).
__global__ void prep_k(
    const float* __restrict__ Wq, const float* __restrict__ Wk,
    const float* __restrict__ Wv, const float* __restrict__ Wo,
    const float* __restrict__ W1, const float* __restrict__ W2,
    const float* __restrict__ x, const float* __restrict__ y,
    u16* __restrict__ WqT, u16* __restrict__ WkT, u16* __restrict__ WvT,
    u16* __restrict__ WoT, u16* __restrict__ W1T, u16* __restrict__ W2T,
    u16* __restrict__ xb, u16* __restrict__ yb) {
  const int z = blockIdx.z;
  if (z < 6) {
    __shared__ u16 tile[32][33];
    const float* in; u16* outp; int R, C;
    switch (z) {
      case 0: in = Wq; outp = WqT; R = 1024; C = 1024; break;
      case 1: in = Wk; outp = WkT; R = 1024; C = 1024; break;
      case 2: in = Wv; outp = WvT; R = 1024; C = 1024; break;
      case 3: in = Wo; outp = WoT; R = 1024; C = 1024; break;
      case 4: in = W1; outp = W1T; R = 1024; C = 4096; break;
      default: in = W2; outp = W2T; R = 4096; C = 1024; break;
    }
    int c0, r0;
    if (z == 5) { c0 = blockIdx.y * 32; r0 = blockIdx.x * 32; }
    else        { c0 = blockIdx.x * 32; r0 = blockIdx.y * 32; }
    if (c0 >= C || r0 >= R) return;
    const int tx = threadIdx.x, ty = threadIdx.y;
    for (int i = ty; i < 32; i += 8)
      tile[i][tx] = f2bf(in[(long)(r0 + i) * C + c0 + tx]);
    __syncthreads();
    for (int i = ty; i < 32; i += 8)
      outp[(long)(c0 + i) * R + r0 + tx] = tile[tx][i];
  } else {
    const float* in = (z == 6) ? x : y;
    u16* outp = (z == 6) ? xb : yb;
    const int lin = (blockIdx.y * 128 + blockIdx.x) * 256 + threadIdx.y * 32 + threadIdx.x;
    float4 v = ((const float4*)in)[lin];
    ((uint2*)outp)[lin] = make_uint2(pk2bf(v.x, v.y) /*order*/ , 0); // placeholder replaced below
  }
}

// NOTE: pk2bf uses +0x8000 (round-nearest, no tie-even); for activations keep
// exact RNE via f2bf to match prior absmax. Re-implement cvt properly:
__global__ __launch_bounds__(256) void cvt2_k(const float* __restrict__ x, const float* __restrict__ y,
                                              u16* __restrict__ xb, u16* __restrict__ yb) {
  const int z = blockIdx.y;
  const float* in = z ? y : x;
  u16* outp = z ? yb : xb;
  const int i = blockIdx.x * 256 + threadIdx.x;
  float4 v = ((const float4*)in)[i];
  unsigned int lo = (unsigned int)f2bf(v.x) | ((unsigned int)f2bf(v.y) << 16);
  unsigned int hi = (unsigned int)f2bf(v.z) | ((unsigned int)f2bf(v.w) << 16);
  ((uint2*)outp)[i] = make_uint2(lo, hi);
}

// ---------------- generic bf16 GEMM: C[M,N] = A[M,K] @ Bt[N,K]^T ----------------
template<int MT, int NT, int OUTF32>
__global__ __launch_bounds__(256) void gemm_bt(
    const u16* __restrict__ A, const u16* __restrict__ Bt,
    const float* __restrict__ bias, void* __restrict__ Cv,
    int K, int lda, int ldb, int ldc,
    long sA, long sB, long sC, int relu) {
  constexpr int BM = MT * 32;
  constexpr int BN = NT * 32;
  __shared__ __align__(16) u16 As[BM * 32];
  __shared__ __align__(16) u16 Bs[BN * 32];
  const int z = blockIdx.z;
  A  += (long)z * sA;
  Bt += (long)z * sB;
  const int tid  = threadIdx.x;
  const int lane = tid & 63, wave = tid >> 6;
  const int quad = lane >> 4, l15 = lane & 15;
  const int wm = wave >> 1, wn = wave & 1;
  const u16* Ab = A  + (long)(blockIdx.y * BM) * lda;
  const u16* Bb = Bt + (long)(blockIdx.x * BN) * ldb;

  f32x4 acc[MT][NT];
#pragma unroll
  for (int i = 0; i < MT; ++i)
#pragma unroll
    for (int j = 0; j < NT; ++j) acc[i][j] = (f32x4){0.f, 0.f, 0.f, 0.f};

  const int r0  = tid >> 2;
  const int kk0 = (tid & 3) * 8;

  for (int kt = 0; kt < K; kt += 32) {
#pragma unroll
    for (int p = 0; p < BM / 64; ++p) {
      __builtin_amdgcn_global_load_lds(
          (const __attribute__((address_space(1))) void*)(Ab + (long)(p * 64 + r0) * lda + kt + kk0),
          (__attribute__((address_space(3))) void*)(&As[p * 2048 + tid * 8]), 16, 0, 0);
    }
#pragma unroll
    for (int p = 0; p < BN / 64; ++p) {
      __builtin_amdgcn_global_load_lds(
          (const __attribute__((address_space(1))) void*)(Bb + (long)(p * 64 + r0) * ldb + kt + kk0),
          (__attribute__((address_space(3))) void*)(&Bs[p * 2048 + tid * 8]), 16, 0, 0);
    }
    __syncthreads();
    short8 af[MT], bfr[NT];
#pragma unroll
    for (int mt = 0; mt < MT; ++mt)
      af[mt] = *(const short8*)&As[(wm * (MT * 16) + mt * 16 + l15) * 32 + quad * 8];
#pragma unroll
    for (int nt = 0; nt < NT; ++nt)
      bfr[nt] = *(const short8*)&Bs[(wn * (NT * 16) + nt * 16 + l15) * 32 + quad * 8];
#pragma unroll
    for (int mt = 0; mt < MT; ++mt)
#pragma unroll
      for (int nt = 0; nt < NT; ++nt)
        acc[mt][nt] = __builtin_amdgcn_mfma_f32_16x16x32_bf16(af[mt], bfr[nt], acc[mt][nt], 0, 0, 0);
    __syncthreads();
  }

#pragma unroll
  for (int nt = 0; nt < NT; ++nt) {
    const int col = blockIdx.x * BN + wn * (NT * 16) + nt * 16 + l15;
    const float bvv = bias ? bias[col] : 0.f;
#pragma unroll
    for (int mt = 0; mt < MT; ++mt) {
#pragma unroll
      for (int r = 0; r < 4; ++r) {
        const int row = blockIdx.y * BM + wm * (MT * 16) + mt * 16 + quad * 4 + r;
        float v = acc[mt][nt][r] + bvv;
        if (relu) v = fmaxf(v, 0.f);
        if (OUTF32) ((float*)Cv)[(long)z * sC + (long)row * ldc + col] = v;
        else        ((u16*)Cv)[(long)z * sC + (long)row * ldc + col] = f2bf(v);
      }
    }
  }
}

// ---------------- QKV batched GEMM (Q pre-scaled by 0.125*log2e) -------------
__global__ __launch_bounds__(256) void qkv_k(
    const u16* __restrict__ xb, const u16* __restrict__ yb,
    const u16* __restrict__ WqT, const u16* __restrict__ WkT, const u16* __restrict__ WvT,
    const float* __restrict__ bq, const float* __restrict__ bk, const float* __restrict__ bv,
    u16* __restrict__ Q, u16* __restrict__ Kp, u16* __restrict__ Vp) {
  __shared__ __align__(16) u16 As[128 * 32];
  __shared__ __align__(16) u16 Bs[128 * 32];
  const int z = blockIdx.z;
  const u16* A  = (z == 0) ? xb : yb;
  const u16* Bt = (z == 0) ? WqT : (z == 1) ? WkT : WvT;
  const float* bias = (z == 0) ? bq : (z == 1) ? bk : bv;
  u16* C = (z == 0) ? Q : (z == 1) ? Kp : Vp;
  const float sc = (z == 0) ? 0.18033688011112042f : 1.0f;  // 0.125*log2(e)
  const int tid  = threadIdx.x;
  const int lane = tid & 63, wave = tid >> 6;
  const int quad = lane >> 4, l15 = lane & 15;
  const int wm = wave >> 1, wn = wave & 1;
  const u16* Ab = A  + (long)(blockIdx.y * 128) * D_;
  const u16* Bb = Bt + (long)(blockIdx.x * 128) * D_;

  f32x4 acc[4][4];
#pragma unroll
  for (int i = 0; i < 4; ++i)
#pragma unroll
    for (int j = 0; j < 4; ++j) acc[i][j] = (f32x4){0.f, 0.f, 0.f, 0.f};

  const int r0  = tid >> 2;
  const int kk0 = (tid & 3) * 8;

  for (int kt = 0; kt < D_; kt += 32) {
#pragma unroll
    for (int p = 0; p < 2; ++p) {
      __builtin_amdgcn_global_load_lds(
          (const __attribute__((address_space(1))) void*)(Ab + (long)(p * 64 + r0) * D_ + kt + kk0),
          (__attribute__((address_space(3))) void*)(&As[p * 2048 + tid * 8]), 16, 0, 0);
      __builtin_amdgcn_global_load_lds(
          (const __attribute__((address_space(1))) void*)(Bb + (long)(p * 64 + r0) * D_ + kt + kk0),
          (__attribute__((address_space(3))) void*)(&Bs[p * 2048 + tid * 8]), 16, 0, 0);
    }
    __syncthreads();
    short8 af[4], bfr[4];
#pragma unroll
    for (int mt = 0; mt < 4; ++mt)
      af[mt] = *(const short8*)&As[(wm * 64 + mt * 16 + l15) * 32 + quad * 8];
#pragma unroll
    for (int nt = 0; nt < 4; ++nt)
      bfr[nt] = *(const short8*)&Bs[(wn * 64 + nt * 16 + l15) * 32 + quad * 8];
#pragma unroll
    for (int mt = 0; mt < 4; ++mt)
#pragma unroll
      for (int nt = 0; nt < 4; ++nt)
        acc[mt][nt] = __builtin_amdgcn_mfma_f32_16x16x32_bf16(af[mt], bfr[nt], acc[mt][nt], 0, 0, 0);
    __syncthreads();
  }

#pragma unroll
  for (int nt = 0; nt < 4; ++nt) {
    const int col = blockIdx.x * 128 + wn * 64 + nt * 16 + l15;
    const float bvv = bias[col];
#pragma unroll
    for (int mt = 0; mt < 4; ++mt) {
#pragma unroll
      for (int r = 0; r < 4; ++r) {
        const int row = blockIdx.y * 128 + wm * 64 + mt * 16 + quad * 4 + r;
        C[(long)row * D_ + col] = f2bf((acc[mt][nt][r] + bvv) * sc);
      }
    }
  }
}

// ---------------- V[b,s,h*64+d] -> Vt[bh][d][s] ----------------
__global__ void vtrans_k(const u16* __restrict__ V, u16* __restrict__ Vt) {
  __shared__ u16 tile[32][33];
  const int bh = blockIdx.z, b = bh >> 4, h = bh & 15;
  const u16* in = V + (long)b * S_ * D_ + h * DK_;
  u16* outp = Vt + (long)bh * DK_ * S_;
  const int s0 = blockIdx.x * 32, d0 = blockIdx.y * 32;
  const int tx = threadIdx.x, ty = threadIdx.y;
  for (int i = ty; i < 32; i += 8)
    tile[i][tx] = in[(long)(s0 + i) * D_ + d0 + tx];
  __syncthreads();
  for (int i = ty; i < 32; i += 8)
    outp[(long)(d0 + i) * S_ + s0 + tx] = tile[tx][i];
}

// ---------------- fused flash attention v3 ----------------
// grid (B*H, S/64), 256 threads (4 waves). Wave w owns q rows [w*16, w*16+16).
// 64 kv-tiles of 32; K/V double-buffered; Q frags persistent; 28KB static LDS.
// Q pre-scaled by 0.125*log2e -> p = mask ? exp2(s) : 0.
__global__ __launch_bounds__(256, 4) void flash_k(
    const u16* __restrict__ Q, const u16* __restrict__ Kp, const u16* __restrict__ Vt,
    const int* __restrict__ mask, u16* __restrict__ ctx) {
  __shared__ __align__(16) u16 sQ[2 * 64 * 32];   // 8KB: [2 d-panels][64 q][32]
  __shared__ __align__(16) u16 sK[2 * 2048];      // 8KB: [2 buf][2 panel][32 kv][32]
  __shared__ __align__(16) u16 sV[2 * 2048];      // 8KB: [2 buf][64 d][32 kv]
  __shared__ __align__(16) u16 sP[64 * 32];       // 4KB: [64 q][32 kv] swizzled

  const int bh = blockIdx.x, qt = blockIdx.y;
  const int b = bh >> 4, h = bh & 15;
  const int tid = threadIdx.x;
  const int w = tid >> 6, lane = tid & 63;
  const int quad = lane >> 4, l15 = lane & 15;
  const int swz = ((l15 ^ (l15 >> 2)) & 3) << 3;

  const u16* Qg  = Q  + ((long)b * S_ + qt * 64) * D_ + h * DK_;
  const u16* Kg  = Kp + (long)b * S_ * D_ + h * DK_;
  const u16* Vtg = Vt + (long)bh * DK_ * S_;
  const int* maskg = mask + (long)b * S_;
  u16* ctxg = ctx + ((long)b * S_ + qt * 64) * D_ + h * DK_;

  const int krow = tid >> 3, kc = tid & 7;
  const u16* kptr = Kg + (long)krow * D_ + kc * 8;
  const int ksw = (kc >> 2) * 1024 + krow * 32 + (kc & 3) * 8;
  const int vrow = tid >> 2, vc = tid & 3;
  const u16* vptr = Vtg + (long)vrow * S_ + vc * 8;
  const int vsw = vrow * 32 + vc * 8;

  uint4 kreg = *(const uint4*)kptr;
  uint4 vreg = *(const uint4*)vptr;

  // stage Q (64 rows x 64 cols)
#pragma unroll
  for (int p = 0; p < 2; ++p) {
    const int idx = p * 256 + tid;
    const int row = idx >> 3, cb = idx & 7;
    uint4 v = *(const uint4*)(Qg + (long)row * D_ + cb * 8);
    *(uint4*)&sQ[(cb >> 2) * 2048 + row * 32 + (cb & 3) * 8] = v;
  }
  *(uint4*)&sK[ksw] = kreg;
  *(uint4*)&sV[vsw] = vreg;
  kreg = *(const uint4*)(kptr + 32 * D_);
  vreg = *(const uint4*)(vptr + 32);
  kptr += 64 * D_;
  vptr += 64;
  __syncthreads();

  short8 qf[2];
#pragma unroll
  for (int kt = 0; kt < 2; ++kt)
    qf[kt] = *(const short8*)&sQ[kt * 2048 + (w * 16 + l15) * 32 + quad * 8];

  float lsum = 0.f;
  f32x4 accO[4];
#pragma unroll
  for (int j = 0; j < 4; ++j) accO[j] = (f32x4){0.f, 0.f, 0.f, 0.f};

  for (int t = 0; t < 64; ++t) {
    if (t) __syncthreads();
    const int buf = (t & 1) ? 2048 : 0;
    const int nbuf = buf ^ 2048;
    if (t < 63) {
      *(uint4*)&sK[nbuf + ksw] = kreg;
      *(uint4*)&sV[nbuf + vsw] = vreg;
      if (t < 62) {
        kreg = *(const uint4*)kptr;
        vreg = *(const uint4*)vptr;
        kptr += 32 * D_;
        vptr += 32;
      }
    }
    const int4 mv0 = *(const int4*)(maskg + t * 32 + quad * 4);
    const int4 mv1 = *(const int4*)(maskg + t * 32 + 16 + quad * 4);

    f32x4 accS[2];
    accS[0] = (f32x4){0.f, 0.f, 0.f, 0.f};
    accS[1] = (f32x4){0.f, 0.f, 0.f, 0.f};
#pragma unroll
    for (int kt = 0; kt < 2; ++kt) {
      short8 kf0 = *(const short8*)&sK[buf + kt * 1024 + l15 * 32 + quad * 8];
      short8 kf1 = *(const short8*)&sK[buf + kt * 1024 + (16 + l15) * 32 + quad * 8];
      accS[0] = __builtin_amdgcn_mfma_f32_16x16x32_bf16(kf0, qf[kt], accS[0], 0, 0, 0);
      accS[1] = __builtin_amdgcn_mfma_f32_16x16x32_bf16(kf1, qf[kt], accS[1], 0, 0, 0);
    }
    // p = mask ? exp2(s) : 0; pack to sP (wave-private rows, no barrier needed)
#pragma unroll
    for (int m = 0; m < 2; ++m) {
      const int4 mv = m ? mv1 : mv0;
      float p0 = mv.x ? __builtin_amdgcn_exp2f(accS[m][0]) : 0.f;
      float p1 = mv.y ? __builtin_amdgcn_exp2f(accS[m][1]) : 0.f;
      float p2 = mv.z ? __builtin_amdgcn_exp2f(accS[m][2]) : 0.f;
      float p3 = mv.w ? __builtin_amdgcn_exp2f(accS[m][3]) : 0.f;
      lsum += (p0 + p1) + (p2 + p3);
      *(uint2*)&sP[(w * 16 + l15) * 32 + ((m * 16 + quad * 4) ^ swz)] =
          make_uint2(pk2bf(p0, p1), pk2bf(p2, p3));
    }
    // PV
    short8 pf = *(const short8*)&sP[(w * 16 + l15) * 32 + ((quad * 8) ^ swz)];
#pragma unroll
    for (int n = 0; n < 4; ++n) {
      short8 vf = *(const short8*)&sV[buf + (n * 16 + l15) * 32 + quad * 8];
      accO[n] = __builtin_amdgcn_mfma_f32_16x16x32_bf16(pf, vf, accO[n], 0, 0, 0);
    }
  }

  // epilogue
  lsum += __shfl_xor(lsum, 16, 64);
  lsum += __shfl_xor(lsum, 32, 64);
  float inv[4];
#pragma unroll
  for (int r = 0; r < 4; ++r)
    inv[r] = 1.f / __shfl(lsum, quad * 4 + r, 64);
#pragma unroll
  for (int n = 0; n < 4; ++n) {
#pragma unroll
    for (int r = 0; r < 4; ++r)
      ctxg[(long)(w * 16 + quad * 4 + r) * D_ + n * 16 + l15] = f2bf(accO[n][r] * inv[r]);
  }
}

// ---------------- add + layernorm helpers ----------------
__device__ __forceinline__ float block_reduce_sum(float v, float* red) {
#pragma unroll
  for (int off = 32; off; off >>= 1) v += __shfl_down(v, off, 64);
  __syncthreads();
  if ((threadIdx.x & 63) == 0) red[threadIdx.x >> 6] = v;
  __syncthreads();
  return red[0] + red[1] + red[2] + red[3];
}

__global__ __launch_bounds__(256) void addln_fb(const float* __restrict__ A, const u16* __restrict__ Bres,
    const float* __restrict__ g, const float* __restrict__ be, u16* __restrict__ outp) {
  __shared__ float red[4];
  const int row = blockIdx.x, tid = threadIdx.x;
  const float4 av = ((const float4*)(A + (long)row * D_))[tid];
  const uint2 bv2 = ((const uint2*)(Bres + (long)row * D_))[tid];
  float xv[4];
  xv[0] = av.x + bf2f((u16)(bv2.x & 0xffff));
  xv[1] = av.y + bf2f((u16)(bv2.x >> 16));
  xv[2] = av.z + bf2f((u16)(bv2.y & 0xffff));
  xv[3] = av.w + bf2f((u16)(bv2.y >> 16));
  float s  = xv[0] + xv[1] + xv[2] + xv[3];
  float ss = xv[0]*xv[0] + xv[1]*xv[1] + xv[2]*xv[2] + xv[3]*xv[3];
  s  = block_reduce_sum(s, red);
  ss = block_reduce_sum(ss, red);
  const float m   = s * (1.0f / 1024.0f);
  const float var = ss * (1.0f / 1024.0f) - m * m;
  const float rs  = rsqrtf(var + 1e-5f);
  const int c0 = tid * 4;
  float v0 = (xv[0] - m) * rs * g[c0 + 0] + be[c0 + 0];
  float v1 = (xv[1] - m) * rs * g[c0 + 1] + be[c0 + 1];
  float v2 = (xv[2] - m) * rs * g[c0 + 2] + be[c0 + 2];
  float v3 = (xv[3] - m) * rs * g[c0 + 3] + be[c0 + 3];
  unsigned int o01 = (unsigned int)f2bf(v0) | ((unsigned int)f2bf(v1) << 16);
  unsigned int o23 = (unsigned int)f2bf(v2) | ((unsigned int)f2bf(v3) << 16);
  ((uint2*)(outp + (long)row * D_))[tid] = make_uint2(o01, o23);
}

// x1 (bf16) + 4 fp32 split-K partials + b2 -> LN -> out (fp32)
__global__ __launch_bounds__(256) void addln4_bf(const u16* __restrict__ A,
    const float* __restrict__ pK, const float* __restrict__ b2,
    const float* __restrict__ g, const float* __restrict__ be, float* __restrict__ outp) {
  __shared__ float red[4];
  const int row = blockIdx.x, tid = threadIdx.x;
  const uint2 av = ((const uint2*)(A + (long)row * D_))[tid];
  const long stride = (long)4096 * 1024;
  const float4 P0 = ((const float4*)(pK + 0 * stride + (long)row * D_))[tid];
  const float4 P1 = ((const float4*)(pK + 1 * stride + (long)row * D_))[tid];
  const float4 P2 = ((const float4*)(pK + 2 * stride + (long)row * D_))[tid];
  const float4 P3 = ((const float4*)(pK + 3 * stride + (long)row * D_))[tid];
  const int c0 = tid * 4;
  float xv[4];
  xv[0] = bf2f((u16)(av.x & 0xffff)) + ((P0.x + P1.x) + (P2.x + P3.x)) + b2[c0 + 0];
  xv[1] = bf2f((u16)(av.x >> 16))    + ((P0.y + P1.y) + (P2.y + P3.y)) + b2[c0 + 1];
  xv[2] = bf2f((u16)(av.y & 0xffff)) + ((P0.z + P1.z) + (P2.z + P3.z)) + b2[c0 + 2];
  xv[3] = bf2f((u16)(av.y >> 16))    + ((P0.w + P1.w) + (P2.w + P3.w)) + b2[c0 + 3];
  float s  = xv[0] + xv[1] + xv[2] + xv[3];
  float ss = xv[0]*xv[0] + xv[1]*xv[1] + xv[2]*xv[2] + xv[3]*xv[3];
  s  = block_reduce_sum(s, red);
  ss = block_reduce_sum(ss, red);
  const float m   = s * (1.0f / 1024.0f);
  const float var = ss * (1.0f / 1024.0f) - m * m;
  const float rs  = rsqrtf(var + 1e-5f);
  float4 o;
  o.x = (xv[0] - m) * rs * g[c0 + 0] + be[c0 + 0];
  o.y = (xv[1] - m) * rs * g[c0 + 1] + be[c0 + 1];
  o.z = (xv[2] - m) * rs * g[c0 + 2] + be[c0 + 2];
  o.w = (xv[3] - m) * rs * g[c0 + 3] + be[c0 + 3];
  ((float4*)(outp + (long)row * D_))[tid] = o;
}

extern "C" void kernel_launch(void* const* d_in, const int* in_sizes, int n_in,
                              void* d_out, int out_size, void* d_ws, size_t ws_size,
                              hipStream_t stream) {
  const float* x   = (const float*)d_in[0];
  const float* y   = (const float*)d_in[1];
  const int* mask  = (const int*)d_in[2];
  const float* Wq = (const float*)d_in[3];  const float* bq = (const float*)d_in[4];
  const float* Wk = (const float*)d_in[5];  const float* bk = (const float*)d_in[6];
  const float* Wv = (const float*)d_in[7];  const float* bv = (const float*)d_in[8];
  const float* Wo = (const float*)d_in[9];  const float* bo = (const float*)d_in[10];
  const float* W1 = (const float*)d_in[11]; const float* b1 = (const float*)d_in[12];
  const float* W2 = (const float*)d_in[13]; const float* b2 = (const float*)d_in[14];
  const float* g1 = (const float*)d_in[15]; const float* be1 = (const float*)d_in[16];
  const float* g2 = (const float*)d_in[17]; const float* be2 = (const float*)d_in[18];
  float* out = (float*)d_out;

  char* w = (char*)d_ws;
  const size_t MB = 1024 * 1024;
  u16* WqT = (u16*)(w + 0 * MB);
  u16* WkT = (u16*)(w + 2 * MB);
  u16* WvT = (u16*)(w + 4 * MB);
  u16* WoT = (u16*)(w + 6 * MB);
  u16* W1T = (u16*)(w + 8 * MB);     // 8MB  [HID][D]
  u16* W2T = (u16*)(w + 16 * MB);    // 8MB  [D][HID]
  u16* xb  = (u16*)(w + 24 * MB);    // dead after qkv -> x1 reuses
  u16* yb  = (u16*)(w + 32 * MB);    // dead after qkv
  u16* Q   = (u16*)(w + 40 * MB);    // dead after flash
  u16* Kp  = (u16*)(w + 48 * MB);    // dead after flash
  u16* Vp  = (u16*)(w + 56 * MB);    // dead after vtrans
  u16* Vt  = (u16*)(w + 64 * MB);    // dead after flash
  u16* ctx = (u16*)(w + 72 * MB);    // dead after Wo gemm
  u16* mha = (u16*)(w + 80 * MB);    // dead after addln_fb
  u16* x1  = (u16*)(w + 24 * MB);    // reuses xb; live through addln4
  u16* h1  = (u16*)(w + 96 * MB);    // 32MB bf16 [4096][4096]
  float* pK = (float*)(w + 32 * MB); // 4 x 16MB fp32 partials (32..96, all dead)

  // prep: 6 weight transposes in one dispatch + x/y cvt
  prep_k<<<dim3(128, 32, 6), dim3(32, 8), 0, stream>>>(Wq, Wk, Wv, Wo, W1, W2, x, y,
      WqT, WkT, WvT, WoT, W1T, W2T, xb, yb);
  cvt2_k<<<dim3(4096, 2), 256, 0, stream>>>(x, y, xb, yb);

  // QKV: one dispatch, 768 blocks (Q pre-scaled)
  qkv_k<<<dim3(8, 32, 3), 256, 0, stream>>>(xb, yb, WqT, WkT, WvT, bq, bk, bv, Q, Kp, Vp);

  vtrans_k<<<dim3(64, 2, 32), dim3(32, 8), 0, stream>>>(Vp, Vt);

  // fused flash attention v3: 1024 blocks, 4/CU
  flash_k<<<dim3(32, 32), 256, 0, stream>>>(Q, Kp, Vt, mask, ctx);

  // output projection + LN1
  gemm_bt<2, 4, 0><<<dim3(8, 64, 1), 256, 0, stream>>>(ctx, WoT, bo, mha,
      1024, 1024, 1024, 1024, 0, 0, 0, 0);
  addln_fb<<<dim3(4096), 256, 0, stream>>>(x, mha, g1, be1, x1);

  // FFN1: 1024 blocks
  gemm_bt<4, 4, 0><<<dim3(32, 32, 1), 256, 0, stream>>>(x1, W1T, b1, h1,
      1024, 1024, 1024, 4096, 0, 0, 0, 1);
  // FFN2: split-K=4, fp32 partials, 1024 blocks
  gemm_bt<4, 4, 1><<<dim3(8, 32, 4), 256, 0, stream>>>(h1, W2T, nullptr, (void*)pK,
      1024, 4096, 4096, 1024, 1024, 1024, (long)4096 * 1024, 0);
  addln4_bf<<<dim3(4096), 256, 0, stream>>>(x1, pK, b2, g2, be2, out);
}

// Round 6
// 411.897 us; speedup vs baseline: 1.8072x; 1.0753x over previous
//
#include <hip/hip_runtime.h>

#define S_ 2048
#define D_ 1024
#define B_ 2
#define H_ 16
#define DK_ 64
#define HID_ 4096

typedef unsigned short u16;
typedef __attribute__((ext_vector_type(8))) short short8;
typedef __attribute__((ext_vector_type(4))) float f32x4;

// frag-linear slot with bank-spreading XOR: panel of 64 slots x 16B
#define SLOT(q16, r16) (((q16) * 16) + ((r16) ^ (q16)))

__device__ __forceinline__ float bf2f(u16 u) {
  return __uint_as_float(((unsigned int)u) << 16);
}
__device__ __forceinline__ u16 f2bf(float f) {
  unsigned int x = __float_as_uint(f);
  x += 0x7fff + ((x >> 16) & 1);
  return (u16)(x >> 16);
}
__device__ __forceinline__ unsigned int pk2bf(float lo, float hi) {
  return ((__float_as_uint(lo) + 0x8000u) >> 16) | ((__float_as_uint(hi) + 0x8000u) & 0xffff0000u);
}

// ---------------- prep: 6 weight transposes (f32 -> bf16, [K,N] -> [N,K]) ----
__global__ void prep_k(
    const float* __restrict__ Wq, const float* __restrict__ Wk,
    const float* __restrict__ Wv, const float* __restrict__ Wo,
    const float* __restrict__ W1, const float* __restrict__ W2,
    u16* __restrict__ WqT, u16* __restrict__ WkT, u16* __restrict__ WvT,
    u16* __restrict__ WoT, u16* __restrict__ W1T, u16* __restrict__ W2T) {
  const int z = blockIdx.z;
  __shared__ u16 tile[32][33];
  const float* in; u16* outp; int R, C;
  switch (z) {
    case 0: in = Wq; outp = WqT; R = 1024; C = 1024; break;
    case 1: in = Wk; outp = WkT; R = 1024; C = 1024; break;
    case 2: in = Wv; outp = WvT; R = 1024; C = 1024; break;
    case 3: in = Wo; outp = WoT; R = 1024; C = 1024; break;
    case 4: in = W1; outp = W1T; R = 1024; C = 4096; break;
    default: in = W2; outp = W2T; R = 4096; C = 1024; break;
  }
  int c0, r0;
  if (z == 5) { c0 = blockIdx.y * 32; r0 = blockIdx.x * 32; }
  else        { c0 = blockIdx.x * 32; r0 = blockIdx.y * 32; }
  if (c0 >= C || r0 >= R) return;
  const int tx = threadIdx.x, ty = threadIdx.y;
  for (int i = ty; i < 32; i += 8)
    tile[i][tx] = f2bf(in[(long)(r0 + i) * C + c0 + tx]);
  __syncthreads();
  for (int i = ty; i < 32; i += 8)
    outp[(long)(c0 + i) * R + r0 + tx] = tile[tx][i];
}

__global__ __launch_bounds__(256) void cvt2_k(const float* __restrict__ x, const float* __restrict__ y,
                                              u16* __restrict__ xb, u16* __restrict__ yb) {
  const int z = blockIdx.y;
  const float* in = z ? y : x;
  u16* outp = z ? yb : xb;
  const int i = blockIdx.x * 256 + threadIdx.x;
  float4 v = ((const float4*)in)[i];
  unsigned int lo = (unsigned int)f2bf(v.x) | ((unsigned int)f2bf(v.y) << 16);
  unsigned int hi = (unsigned int)f2bf(v.z) | ((unsigned int)f2bf(v.w) << 16);
  ((uint2*)outp)[i] = make_uint2(lo, hi);
}

// ---------------- generic bf16 GEMM: C[M,N] = A[M,K] @ Bt[N,K]^T ----------------
template<int MT, int NT, int OUTF32>
__global__ __launch_bounds__(256) void gemm_bt(
    const u16* __restrict__ A, const u16* __restrict__ Bt,
    const float* __restrict__ bias, void* __restrict__ Cv,
    int K, int lda, int ldb, int ldc,
    long sA, long sB, long sC, int relu) {
  constexpr int BM = MT * 32;
  constexpr int BN = NT * 32;
  __shared__ __align__(16) u16 As[BM * 32];
  __shared__ __align__(16) u16 Bs[BN * 32];
  const int z = blockIdx.z;
  A  += (long)z * sA;
  Bt += (long)z * sB;
  const int tid  = threadIdx.x;
  const int lane = tid & 63, wave = tid >> 6;
  const int quad = lane >> 4, l15 = lane & 15;
  const int wm = wave >> 1, wn = wave & 1;
  const u16* Ab = A  + (long)(blockIdx.y * BM) * lda;
  const u16* Bb = Bt + (long)(blockIdx.x * BN) * ldb;

  f32x4 acc[MT][NT];
#pragma unroll
  for (int i = 0; i < MT; ++i)
#pragma unroll
    for (int j = 0; j < NT; ++j) acc[i][j] = (f32x4){0.f, 0.f, 0.f, 0.f};

  const int r0  = tid >> 2;
  const int kk0 = (tid & 3) * 8;

  for (int kt = 0; kt < K; kt += 32) {
#pragma unroll
    for (int p = 0; p < BM / 64; ++p) {
      __builtin_amdgcn_global_load_lds(
          (const __attribute__((address_space(1))) void*)(Ab + (long)(p * 64 + r0) * lda + kt + kk0),
          (__attribute__((address_space(3))) void*)(&As[p * 2048 + tid * 8]), 16, 0, 0);
    }
#pragma unroll
    for (int p = 0; p < BN / 64; ++p) {
      __builtin_amdgcn_global_load_lds(
          (const __attribute__((address_space(1))) void*)(Bb + (long)(p * 64 + r0) * ldb + kt + kk0),
          (__attribute__((address_space(3))) void*)(&Bs[p * 2048 + tid * 8]), 16, 0, 0);
    }
    __syncthreads();
    short8 af[MT], bfr[NT];
#pragma unroll
    for (int mt = 0; mt < MT; ++mt)
      af[mt] = *(const short8*)&As[(wm * (MT * 16) + mt * 16 + l15) * 32 + quad * 8];
#pragma unroll
    for (int nt = 0; nt < NT; ++nt)
      bfr[nt] = *(const short8*)&Bs[(wn * (NT * 16) + nt * 16 + l15) * 32 + quad * 8];
#pragma unroll
    for (int mt = 0; mt < MT; ++mt)
#pragma unroll
      for (int nt = 0; nt < NT; ++nt)
        acc[mt][nt] = __builtin_amdgcn_mfma_f32_16x16x32_bf16(af[mt], bfr[nt], acc[mt][nt], 0, 0, 0);
    __syncthreads();
  }

#pragma unroll
  for (int nt = 0; nt < NT; ++nt) {
    const int col = blockIdx.x * BN + wn * (NT * 16) + nt * 16 + l15;
    const float bvv = bias ? bias[col] : 0.f;
#pragma unroll
    for (int mt = 0; mt < MT; ++mt) {
#pragma unroll
      for (int r = 0; r < 4; ++r) {
        const int row = blockIdx.y * BM + wm * (MT * 16) + mt * 16 + quad * 4 + r;
        float v = acc[mt][nt][r] + bvv;
        if (relu) v = fmaxf(v, 0.f);
        if (OUTF32) ((float*)Cv)[(long)z * sC + (long)row * ldc + col] = v;
        else        ((u16*)Cv)[(long)z * sC + (long)row * ldc + col] = f2bf(v);
      }
    }
  }
}

// ---------------- QKV batched GEMM (Q pre-scaled by 0.125*log2e) -------------
__global__ __launch_bounds__(256) void qkv_k(
    const u16* __restrict__ xb, const u16* __restrict__ yb,
    const u16* __restrict__ WqT, const u16* __restrict__ WkT, const u16* __restrict__ WvT,
    const float* __restrict__ bq, const float* __restrict__ bk, const float* __restrict__ bv,
    u16* __restrict__ Q, u16* __restrict__ Kp, u16* __restrict__ Vp) {
  __shared__ __align__(16) u16 As[128 * 32];
  __shared__ __align__(16) u16 Bs[128 * 32];
  const int z = blockIdx.z;
  const u16* A  = (z == 0) ? xb : yb;
  const u16* Bt = (z == 0) ? WqT : (z == 1) ? WkT : WvT;
  const float* bias = (z == 0) ? bq : (z == 1) ? bk : bv;
  u16* C = (z == 0) ? Q : (z == 1) ? Kp : Vp;
  const float sc = (z == 0) ? 0.18033688011112042f : 1.0f;  // 0.125*log2(e)
  const int tid  = threadIdx.x;
  const int lane = tid & 63, wave = tid >> 6;
  const int quad = lane >> 4, l15 = lane & 15;
  const int wm = wave >> 1, wn = wave & 1;
  const u16* Ab = A  + (long)(blockIdx.y * 128) * D_;
  const u16* Bb = Bt + (long)(blockIdx.x * 128) * D_;

  f32x4 acc[4][4];
#pragma unroll
  for (int i = 0; i < 4; ++i)
#pragma unroll
    for (int j = 0; j < 4; ++j) acc[i][j] = (f32x4){0.f, 0.f, 0.f, 0.f};

  const int r0  = tid >> 2;
  const int kk0 = (tid & 3) * 8;

  for (int kt = 0; kt < D_; kt += 32) {
#pragma unroll
    for (int p = 0; p < 2; ++p) {
      __builtin_amdgcn_global_load_lds(
          (const __attribute__((address_space(1))) void*)(Ab + (long)(p * 64 + r0) * D_ + kt + kk0),
          (__attribute__((address_space(3))) void*)(&As[p * 2048 + tid * 8]), 16, 0, 0);
      __builtin_amdgcn_global_load_lds(
          (const __attribute__((address_space(1))) void*)(Bb + (long)(p * 64 + r0) * D_ + kt + kk0),
          (__attribute__((address_space(3))) void*)(&Bs[p * 2048 + tid * 8]), 16, 0, 0);
    }
    __syncthreads();
    short8 af[4], bfr[4];
#pragma unroll
    for (int mt = 0; mt < 4; ++mt)
      af[mt] = *(const short8*)&As[(wm * 64 + mt * 16 + l15) * 32 + quad * 8];
#pragma unroll
    for (int nt = 0; nt < 4; ++nt)
      bfr[nt] = *(const short8*)&Bs[(wn * 64 + nt * 16 + l15) * 32 + quad * 8];
#pragma unroll
    for (int mt = 0; mt < 4; ++mt)
#pragma unroll
      for (int nt = 0; nt < 4; ++nt)
        acc[mt][nt] = __builtin_amdgcn_mfma_f32_16x16x32_bf16(af[mt], bfr[nt], acc[mt][nt], 0, 0, 0);
    __syncthreads();
  }

#pragma unroll
  for (int nt = 0; nt < 4; ++nt) {
    const int col = blockIdx.x * 128 + wn * 64 + nt * 16 + l15;
    const float bvv = bias[col];
#pragma unroll
    for (int mt = 0; mt < 4; ++mt) {
#pragma unroll
      for (int r = 0; r < 4; ++r) {
        const int row = blockIdx.y * 128 + wm * 64 + mt * 16 + quad * 4 + r;
        C[(long)row * D_ + col] = f2bf((acc[mt][nt][r] + bvv) * sc);
      }
    }
  }
}

// ---------------- V[b,s,h*64+d] -> Vt[bh][d][s] ----------------
__global__ void vtrans_k(const u16* __restrict__ V, u16* __restrict__ Vt) {
  __shared__ u16 tile[32][33];
  const int bh = blockIdx.z, b = bh >> 4, h = bh & 15;
  const u16* in = V + (long)b * S_ * D_ + h * DK_;
  u16* outp = Vt + (long)bh * DK_ * S_;
  const int s0 = blockIdx.x * 32, d0 = blockIdx.y * 32;
  const int tx = threadIdx.x, ty = threadIdx.y;
  for (int i = ty; i < 32; i += 8)
    tile[i][tx] = in[(long)(s0 + i) * D_ + d0 + tx];
  __syncthreads();
  for (int i = ty; i < 32; i += 8)
    outp[(long)(d0 + i) * S_ + s0 + tx] = tile[tx][i];
}

// ---------------- fused flash attention v4: frag-linear swizzled LDS ----------
// grid (B*H, S/128), 256 thr (4 waves). Wave w owns q in [w*32, w*32+32).
// 64 kv-tiles of 32. All LDS tiles stored in MFMA-frag order: panel of 64
// slots x 16B, slot = SLOT(q16, r16); every ds_read_b128 is base+lane*16B
// (conflict-free); staging/P writes spread via the XOR.
__global__ __launch_bounds__(256, 4) void flash_k(
    const u16* __restrict__ Q, const u16* __restrict__ Kp, const u16* __restrict__ Vt,
    const int* __restrict__ mask, u16* __restrict__ ctx) {
  __shared__ __align__(16) u16 sQ[8192];       // 16KB: 8 panels [f*2+kt]
  __shared__ __align__(16) u16 sK[2][2048];    // 8KB: 2 buf x 4 panels [mk*2+kt]
  __shared__ __align__(16) u16 sV[2][2048];    // 8KB: 2 buf x 4 panels [n]
  __shared__ __align__(16) u16 sP[4][1024];    // 8KB: per-wave 2 panels [mf]

  const int bh = blockIdx.x, qt = blockIdx.y;
  const int b = bh >> 4, h = bh & 15;
  const int tid = threadIdx.x;
  const int w = tid >> 6, lane = tid & 63;
  const int quad = lane >> 4, l15 = lane & 15;

  const u16* Qg  = Q  + ((long)b * S_ + qt * 128) * D_ + h * DK_;
  const u16* Kg  = Kp + (long)b * S_ * D_ + h * DK_;
  const u16* Vtg = Vt + (long)bh * DK_ * S_;
  const int* maskg = mask + (long)b * S_;
  u16* ctxg = ctx + ((long)b * S_ + qt * 128) * D_ + h * DK_;

  // staging maps
  const int krow = tid >> 3, kc = tid & 7;   // K: 32 kv-rows x 8 d-chunks
  const u16* kptr = Kg + (long)krow * D_ + kc * 8;
  const int ksw = (((krow >> 4) * 2 + (kc >> 2)) * 64 + SLOT(kc & 3, krow & 15)) * 8;
  const int vrow = tid >> 2, vc = tid & 3;   // V: 64 d-rows x 4 kv-chunks
  const u16* vptr = Vtg + (long)vrow * S_ + vc * 8;
  const int vsw = ((vrow >> 4) * 64 + SLOT(vc, vrow & 15)) * 8;

  uint4 kreg = *(const uint4*)kptr;
  uint4 vreg = *(const uint4*)vptr;

  // stage Q: 128 rows x 64 cols, frag-linear
#pragma unroll
  for (int p = 0; p < 4; ++p) {
    const int idx = p * 256 + tid;
    const int row = idx >> 3, cb = idx & 7;
    uint4 v = *(const uint4*)(Qg + (long)row * D_ + cb * 8);
    *(uint4*)&sQ[(((row >> 4) * 2 + (cb >> 2)) * 64 + SLOT(cb & 3, row & 15)) * 8] = v;
  }
  *(uint4*)&sK[0][ksw] = kreg;
  *(uint4*)&sV[0][vsw] = vreg;
  kreg = *(const uint4*)(kptr + 32 * D_);
  vreg = *(const uint4*)(vptr + 32);
  kptr += 64 * D_;
  vptr += 64;
  __syncthreads();

  const int rslot = SLOT(quad, l15) * 8;   // reader offset within a panel

  short8 qf[2][2];
#pragma unroll
  for (int mf = 0; mf < 2; ++mf)
#pragma unroll
    for (int kt = 0; kt < 2; ++kt)
      qf[mf][kt] = *(const short8*)&sQ[(((w * 2 + mf) * 2 + kt) * 64) * 8 + rslot];

  float lsum[2] = {0.f, 0.f};
  f32x4 accO[2][4];
#pragma unroll
  for (int i = 0; i < 2; ++i)
#pragma unroll
    for (int j = 0; j < 4; ++j) accO[i][j] = (f32x4){0.f, 0.f, 0.f, 0.f};

  for (int t = 0; t < 64; ++t) {
    if (t) __syncthreads();
    const int buf = t & 1, nb = buf ^ 1;
    if (t < 63) {
      *(uint4*)&sK[nb][ksw] = kreg;
      *(uint4*)&sV[nb][vsw] = vreg;
      if (t < 62) {
        kreg = *(const uint4*)kptr;
        vreg = *(const uint4*)vptr;
        kptr += 32 * D_;
        vptr += 32;
      }
    }
    // scores: Sc^T[kv 32][q 32/wave]
    f32x4 accS[2][2];   // [mk][mf]
#pragma unroll
    for (int i = 0; i < 2; ++i)
#pragma unroll
      for (int j = 0; j < 2; ++j) accS[i][j] = (f32x4){0.f, 0.f, 0.f, 0.f};
#pragma unroll
    for (int kt = 0; kt < 2; ++kt) {
      short8 kf0 = *(const short8*)&sK[buf][(kt * 64) * 8 + rslot];
      short8 kf1 = *(const short8*)&sK[buf][((2 + kt) * 64) * 8 + rslot];
#pragma unroll
      for (int mf = 0; mf < 2; ++mf) {
        accS[0][mf] = __builtin_amdgcn_mfma_f32_16x16x32_bf16(kf0, qf[mf][kt], accS[0][mf], 0, 0, 0);
        accS[1][mf] = __builtin_amdgcn_mfma_f32_16x16x32_bf16(kf1, qf[mf][kt], accS[1][mf], 0, 0, 0);
      }
    }
    // p = mask ? exp2(s) : 0; write to per-wave sP in frag-linear layout
    const int4 mv0 = *(const int4*)(maskg + t * 32 + quad * 4);
    const int4 mv1 = *(const int4*)(maskg + t * 32 + 16 + quad * 4);
#pragma unroll
    for (int mk = 0; mk < 2; ++mk) {
      const int4 mv = mk ? mv1 : mv0;
      const int qt2 = mk * 2 + (quad >> 1);
      const int j0 = (quad & 1) * 4;
#pragma unroll
      for (int mf = 0; mf < 2; ++mf) {
        float p0 = mv.x ? __builtin_amdgcn_exp2f(accS[mk][mf][0]) : 0.f;
        float p1 = mv.y ? __builtin_amdgcn_exp2f(accS[mk][mf][1]) : 0.f;
        float p2 = mv.z ? __builtin_amdgcn_exp2f(accS[mk][mf][2]) : 0.f;
        float p3 = mv.w ? __builtin_amdgcn_exp2f(accS[mk][mf][3]) : 0.f;
        lsum[mf] += (p0 + p1) + (p2 + p3);
        *(uint2*)&sP[w][(mf * 64 + SLOT(qt2, l15)) * 8 + j0] =
            make_uint2(pk2bf(p0, p1), pk2bf(p2, p3));
      }
    }
    // PV: O[q 32][d 64] += P @ V
    short8 pf0 = *(const short8*)&sP[w][0 + rslot];
    short8 pf1 = *(const short8*)&sP[w][64 * 8 + rslot];
#pragma unroll
    for (int n = 0; n < 4; ++n) {
      short8 vf = *(const short8*)&sV[buf][(n * 64) * 8 + rslot];
      accO[0][n] = __builtin_amdgcn_mfma_f32_16x16x32_bf16(pf0, vf, accO[0][n], 0, 0, 0);
      accO[1][n] = __builtin_amdgcn_mfma_f32_16x16x32_bf16(pf1, vf, accO[1][n], 0, 0, 0);
    }
  }

  // epilogue
#pragma unroll
  for (int mf = 0; mf < 2; ++mf) {
    lsum[mf] += __shfl_xor(lsum[mf], 16, 64);
    lsum[mf] += __shfl_xor(lsum[mf], 32, 64);
  }
#pragma unroll
  for (int mf = 0; mf < 2; ++mf) {
    float inv[4];
#pragma unroll
    for (int r = 0; r < 4; ++r)
      inv[r] = 1.f / __shfl(lsum[mf], quad * 4 + r, 64);
#pragma unroll
    for (int n = 0; n < 4; ++n) {
#pragma unroll
      for (int r = 0; r < 4; ++r)
        ctxg[(long)(w * 32 + mf * 16 + quad * 4 + r) * D_ + n * 16 + l15] =
            f2bf(accO[mf][n][r] * inv[r]);
    }
  }
}

// ---------------- add + layernorm helpers ----------------
__device__ __forceinline__ float block_reduce_sum(float v, float* red) {
#pragma unroll
  for (int off = 32; off; off >>= 1) v += __shfl_down(v, off, 64);
  __syncthreads();
  if ((threadIdx.x & 63) == 0) red[threadIdx.x >> 6] = v;
  __syncthreads();
  return red[0] + red[1] + red[2] + red[3];
}

// x (fp32) + mha0 + mha1 (bf16 split-K partials) + bo -> LN -> x1 (bf16)
__global__ __launch_bounds__(256) void addln_fb(const float* __restrict__ A,
    const u16* __restrict__ M0, const u16* __restrict__ M1, const float* __restrict__ bo,
    const float* __restrict__ g, const float* __restrict__ be, u16* __restrict__ outp) {
  __shared__ float red[4];
  const int row = blockIdx.x, tid = threadIdx.x;
  const float4 av = ((const float4*)(A + (long)row * D_))[tid];
  const uint2 m0 = ((const uint2*)(M0 + (long)row * D_))[tid];
  const uint2 m1 = ((const uint2*)(M1 + (long)row * D_))[tid];
  const int c0 = tid * 4;
  float xv[4];
  xv[0] = av.x + bf2f((u16)(m0.x & 0xffff)) + bf2f((u16)(m1.x & 0xffff)) + bo[c0 + 0];
  xv[1] = av.y + bf2f((u16)(m0.x >> 16))    + bf2f((u16)(m1.x >> 16))    + bo[c0 + 1];
  xv[2] = av.z + bf2f((u16)(m0.y & 0xffff)) + bf2f((u16)(m1.y & 0xffff)) + bo[c0 + 2];
  xv[3] = av.w + bf2f((u16)(m0.y >> 16))    + bf2f((u16)(m1.y >> 16))    + bo[c0 + 3];
  float s  = xv[0] + xv[1] + xv[2] + xv[3];
  float ss = xv[0]*xv[0] + xv[1]*xv[1] + xv[2]*xv[2] + xv[3]*xv[3];
  s  = block_reduce_sum(s, red);
  ss = block_reduce_sum(ss, red);
  const float m   = s * (1.0f / 1024.0f);
  const float var = ss * (1.0f / 1024.0f) - m * m;
  const float rs  = rsqrtf(var + 1e-5f);
  float v0 = (xv[0] - m) * rs * g[c0 + 0] + be[c0 + 0];
  float v1 = (xv[1] - m) * rs * g[c0 + 1] + be[c0 + 1];
  float v2 = (xv[2] - m) * rs * g[c0 + 2] + be[c0 + 2];
  float v3 = (xv[3] - m) * rs * g[c0 + 3] + be[c0 + 3];
  unsigned int o01 = (unsigned int)f2bf(v0) | ((unsigned int)f2bf(v1) << 16);
  unsigned int o23 = (unsigned int)f2bf(v2) | ((unsigned int)f2bf(v3) << 16);
  ((uint2*)(outp + (long)row * D_))[tid] = make_uint2(o01, o23);
}

// x1 (bf16) + ff0 + ff1 (bf16 split-K partials) + b2 -> LN -> out (fp32)
__global__ __launch_bounds__(256) void addln2_bf(const u16* __restrict__ A,
    const u16* __restrict__ F0, const u16* __restrict__ F1, const float* __restrict__ b2,
    const float* __restrict__ g, const float* __restrict__ be, float* __restrict__ outp) {
  __shared__ float red[4];
  const int row = blockIdx.x, tid = threadIdx.x;
  const uint2 av = ((const uint2*)(A + (long)row * D_))[tid];
  const uint2 f0 = ((const uint2*)(F0 + (long)row * D_))[tid];
  const uint2 f1 = ((const uint2*)(F1 + (long)row * D_))[tid];
  const int c0 = tid * 4;
  float xv[4];
  xv[0] = bf2f((u16)(av.x & 0xffff)) + bf2f((u16)(f0.x & 0xffff)) + bf2f((u16)(f1.x & 0xffff)) + b2[c0 + 0];
  xv[1] = bf2f((u16)(av.x >> 16))    + bf2f((u16)(f0.x >> 16))    + bf2f((u16)(f1.x >> 16))    + b2[c0 + 1];
  xv[2] = bf2f((u16)(av.y & 0xffff)) + bf2f((u16)(f0.y & 0xffff)) + bf2f((u16)(f1.y & 0xffff)) + b2[c0 + 2];
  xv[3] = bf2f((u16)(av.y >> 16))    + bf2f((u16)(f0.y >> 16))    + bf2f((u16)(f1.y >> 16))    + b2[c0 + 3];
  float s  = xv[0] + xv[1] + xv[2] + xv[3];
  float ss = xv[0]*xv[0] + xv[1]*xv[1] + xv[2]*xv[2] + xv[3]*xv[3];
  s  = block_reduce_sum(s, red);
  ss = block_reduce_sum(ss, red);
  const float m   = s * (1.0f / 1024.0f);
  const float var = ss * (1.0f / 1024.0f) - m * m;
  const float rs  = rsqrtf(var + 1e-5f);
  float4 o;
  o.x = (xv[0] - m) * rs * g[c0 + 0] + be[c0 + 0];
  o.y = (xv[1] - m) * rs * g[c0 + 1] + be[c0 + 1];
  o.z = (xv[2] - m) * rs * g[c0 + 2] + be[c0 + 2];
  o.w = (xv[3] - m) * rs * g[c0 + 3] + be[c0 + 3];
  ((float4*)(outp + (long)row * D_))[tid] = o;
}

extern "C" void kernel_launch(void* const* d_in, const int* in_sizes, int n_in,
                              void* d_out, int out_size, void* d_ws, size_t ws_size,
                              hipStream_t stream) {
  const float* x   = (const float*)d_in[0];
  const float* y   = (const float*)d_in[1];
  const int* mask  = (const int*)d_in[2];
  const float* Wq = (const float*)d_in[3];  const float* bq = (const float*)d_in[4];
  const float* Wk = (const float*)d_in[5];  const float* bk = (const float*)d_in[6];
  const float* Wv = (const float*)d_in[7];  const float* bv = (const float*)d_in[8];
  const float* Wo = (const float*)d_in[9];  const float* bo = (const float*)d_in[10];
  const float* W1 = (const float*)d_in[11]; const float* b1 = (const float*)d_in[12];
  const float* W2 = (const float*)d_in[13]; const float* b2 = (const float*)d_in[14];
  const float* g1 = (const float*)d_in[15]; const float* be1 = (const float*)d_in[16];
  const float* g2 = (const float*)d_in[17]; const float* be2 = (const float*)d_in[18];
  float* out = (float*)d_out;

  char* w = (char*)d_ws;
  const size_t MB = 1024 * 1024;
  u16* WqT = (u16*)(w + 0 * MB);
  u16* WkT = (u16*)(w + 2 * MB);
  u16* WvT = (u16*)(w + 4 * MB);
  u16* WoT = (u16*)(w + 6 * MB);
  u16* W1T = (u16*)(w + 8 * MB);     // 8MB  [HID][D]
  u16* W2T = (u16*)(w + 16 * MB);    // 8MB  [D][HID]
  u16* xb  = (u16*)(w + 24 * MB);    // dead after qkv; x1 reuses
  u16* yb  = (u16*)(w + 32 * MB);    // dead after qkv
  u16* Q   = (u16*)(w + 40 * MB);    // dead after flash; ff partials reuse
  u16* Kp  = (u16*)(w + 48 * MB);    // dead after flash
  u16* Vp  = (u16*)(w + 56 * MB);    // dead after vtrans
  u16* Vt  = (u16*)(w + 64 * MB);    // dead after flash
  u16* ctx = (u16*)(w + 72 * MB);    // dead after Wo gemm
  u16* mha = (u16*)(w + 80 * MB);    // 2 x 8MB bf16 split-K partials (80..96)
  u16* x1  = (u16*)(w + 24 * MB);    // reuses xb; live through addln2
  u16* h1  = (u16*)(w + 96 * MB);    // 32MB bf16 [4096][4096]
  u16* ff  = (u16*)(w + 40 * MB);    // 2 x 8MB bf16 split-K partials (40..56)

  // prep: 6 weight transposes + activations cvt
  prep_k<<<dim3(128, 32, 6), dim3(32, 8), 0, stream>>>(Wq, Wk, Wv, Wo, W1, W2,
      WqT, WkT, WvT, WoT, W1T, W2T);
  cvt2_k<<<dim3(4096, 2), 256, 0, stream>>>(x, y, xb, yb);

  // QKV: one dispatch, 768 blocks (Q pre-scaled)
  qkv_k<<<dim3(8, 32, 3), 256, 0, stream>>>(xb, yb, WqT, WkT, WvT, bq, bk, bv, Q, Kp, Vp);

  vtrans_k<<<dim3(64, 2, 32), dim3(32, 8), 0, stream>>>(Vp, Vt);

  // fused flash attention v4: 512 blocks, 2/CU, conflict-free LDS
  flash_k<<<dim3(32, 16), 256, 0, stream>>>(Q, Kp, Vt, mask, ctx);

  // output projection: split-K=2, bf16 partials (512 blocks); bo folded into LN1
  gemm_bt<4, 4, 0><<<dim3(8, 32, 2), 256, 0, stream>>>(ctx, WoT, nullptr, mha,
      512, 1024, 1024, 1024, 512, 512, (long)4096 * 1024, 0);
  addln_fb<<<dim3(4096), 256, 0, stream>>>(x, mha, mha + (long)4096 * 1024, bo, g1, be1, x1);

  // FFN1: 1024 blocks
  gemm_bt<4, 4, 0><<<dim3(32, 32, 1), 256, 0, stream>>>(x1, W1T, b1, h1,
      1024, 1024, 1024, 4096, 0, 0, 0, 1);
  // FFN2: split-K=2, bf16 partials (512 blocks); b2 folded into LN2
  gemm_bt<4, 4, 0><<<dim3(8, 32, 2), 256, 0, stream>>>(h1, W2T, nullptr, ff,
      2048, 4096, 4096, 1024, 2048, 2048, (long)4096 * 1024, 0);
  addln2_bf<<<dim3(4096), 256, 0, stream>>>(x1, ff, ff + (long)4096 * 1024, b2, g2, be2, out);
}